// Round 2
// baseline (787.681 us; speedup 1.0000x reference)
//
#include <hip/hip_runtime.h>
#include <hip/hip_bf16.h>
#include <stdint.h>

typedef unsigned short ushort_t;
typedef __attribute__((ext_vector_type(8))) short short8;
typedef __attribute__((ext_vector_type(16))) float f32x16;

#define DEV __device__ __forceinline__

DEV int refl(int j) { return j < 0 ? -j : (j > 63 ? 126 - j : j); }

DEV void gload_lds16(const void* g, void* l) {
  __builtin_amdgcn_global_load_lds(
      (const __attribute__((address_space(1))) unsigned int*)g,
      (__attribute__((address_space(3))) unsigned int*)l, 16, 0, 0);
}

// ---------------------------------------------------------------- weights prep
__global__ __launch_bounds__(256) void k_weights(
    const float* __restrict__ w1, const float* __restrict__ w2,
    const float* __restrict__ wt1, const float* __restrict__ bt1,
    const float* __restrict__ wt2, const float* __restrict__ bt2,
    float* __restrict__ W1t, float* __restrict__ W2t,
    float* __restrict__ Wcat, float* __restrict__ beff) {
  int id = blockIdx.x * 256 + threadIdx.x;
  if (id < 36864) {
    int co = id & 63, k = id >> 6;
    int tap = k >> 6, ci = k & 63;
    W1t[k * 64 + co] = w1[(co * 64 + ci) * 9 + tap];
  } else if (id < 73728) {
    int rel = id - 36864;
    int co = rel & 63, k = rel >> 6;
    int tap = k >> 6, ci = k & 63;
    W2t[k * 64 + co] = w2[(co * 64 + ci) * 9 + tap];
  } else if (id < 81920) {
    int rel = id - 73728;
    int co = rel & 63, k = rel >> 6;  // k in [0,128)
    Wcat[k * 64 + co] = wt2[co * 192 + k];
  } else if (id < 98304) {
    int rel = id - 81920;
    int co = rel & 63, j = rel >> 6;  // j in [0,256)
    float s = 0.f;
    for (int ct = 0; ct < 64; ++ct) s += wt2[co * 192 + 128 + ct] * wt1[ct * 256 + j];
    Wcat[(128 + j) * 64 + co] = s;
  } else if (id < 98368) {
    int co = id - 98304;
    float s = bt2[co];
    for (int ct = 0; ct < 64; ++ct) s += wt2[co * 192 + 128 + ct] * bt1[ct];
    beff[co] = s;
  }
}

// ---------------------------------------------------------------- NCHW -> NHWC
__global__ __launch_bounds__(256) void k_transpose(const float* __restrict__ x,
                                                   float* __restrict__ xt) {
  __shared__ float tile[64][65];
  int wg = blockIdx.x;
  int b = wg >> 6, pt = wg & 63;
  int t = threadIdx.x;
  int lane = t & 63, grp = t >> 6;
  const float* xb = x + ((size_t)b * 64) * 4096 + pt * 64;
#pragma unroll
  for (int j = 0; j < 16; ++j) {
    int c = j * 4 + grp;
    tile[c][lane] = xb[(size_t)c * 4096 + lane];
  }
  __syncthreads();
  float* xtb = xt + ((size_t)b * 4096 + (size_t)pt * 64) * 64;
#pragma unroll
  for (int j = 0; j < 16; ++j) {
    int p = j * 4 + grp;
    xtb[p * 64 + lane] = tile[lane][p];
  }
}

// ------------------------------------------- unfold (reflect) -> bf16 + norms
__global__ __launch_bounds__(256) void k_unfold(const float* __restrict__ xt,
                                                __hip_bfloat16* __restrict__ Xhi,
                                                double* __restrict__ norm2,
                                                float* __restrict__ invn) {
  int w = threadIdx.x >> 6, lane = threadIdx.x & 63;
  int gl = blockIdx.x * 4 + w;
  int b = gl >> 12, l = gl & 4095;
  int y = l >> 6, xq = l & 63;
  const float* xb = xt + ((size_t)b * 4096) * 64;
  __hip_bfloat16* out = Xhi + (size_t)gl * 576;
  double s = 0.0;
#pragma unroll
  for (int tap = 0; tap < 9; ++tap) {
    int kh = tap / 3, kw = tap % 3;
    int gy = refl(y + kh - 1), gx = refl(xq + kw - 1);
    float v = xb[(gy * 64 + gx) * 64 + lane];
    out[tap * 64 + lane] = __float2bfloat16(v);
    s += (double)v * (double)v;
  }
#pragma unroll
  for (int off = 32; off; off >>= 1) s += __shfl_xor(s, off, 64);
  if (lane == 0) {
    double n = sqrt(s);
    if (n < 1e-12) n = 1e-12;
    norm2[gl] = s;
    invn[gl] = (float)(1.0 / n);
  }
}

// ---------------------------------------------------------------- 3x3 conv f32
__global__ __launch_bounds__(256) void k_conv3x3(const float* __restrict__ in_t,
                                                 const float* __restrict__ Wt,
                                                 const float* __restrict__ bias,
                                                 float* __restrict__ out_t,
                                                 int do_relu) {
  __shared__ float X[16][580];
  int t = threadIdx.x;
  int p0 = blockIdx.x * 16;
  int b = p0 >> 12;
  int pl = p0 & 4095;
  const float* inb = in_t + ((size_t)b * 4096) * 64;
  {
    int lane = t & 63, grp = t >> 6;
#pragma unroll
    for (int j = 0; j < 4; ++j) {
      int px = grp * 4 + j;
      int p = pl + px;
      int y = p >> 6, xq = p & 63;
#pragma unroll
      for (int tap = 0; tap < 9; ++tap) {
        int kh = tap / 3, kw = tap % 3;
        int yy = y + kh - 1, xx = xq + kw - 1;
        float v = (yy >= 0 && yy < 64 && xx >= 0 && xx < 64)
                      ? inb[(yy * 64 + xx) * 64 + lane] : 0.f;
        X[px][tap * 64 + lane] = v;
      }
    }
  }
  __syncthreads();
  int px = t & 15, cog = t >> 4;
  const float* Wp = Wt + cog * 4;
  float acc0 = bias[cog * 4 + 0], acc1 = bias[cog * 4 + 1];
  float acc2 = bias[cog * 4 + 2], acc3 = bias[cog * 4 + 3];
#pragma unroll 2
  for (int k = 0; k < 576; k += 4) {
    float4 xv = *(const float4*)&X[px][k];
    float4 w0 = *(const float4*)&Wp[(k + 0) * 64];
    float4 w1 = *(const float4*)&Wp[(k + 1) * 64];
    float4 w2 = *(const float4*)&Wp[(k + 2) * 64];
    float4 w3 = *(const float4*)&Wp[(k + 3) * 64];
    acc0 += w0.x * xv.x + w1.x * xv.y + w2.x * xv.z + w3.x * xv.w;
    acc1 += w0.y * xv.x + w1.y * xv.y + w2.y * xv.z + w3.y * xv.w;
    acc2 += w0.z * xv.x + w1.z * xv.y + w2.z * xv.z + w3.z * xv.w;
    acc3 += w0.w * xv.x + w1.w * xv.y + w2.w * xv.z + w3.w * xv.w;
  }
  if (do_relu) {
    acc0 = fmaxf(acc0, 0.f); acc1 = fmaxf(acc1, 0.f);
    acc2 = fmaxf(acc2, 0.f); acc3 = fmaxf(acc3, 0.f);
  }
  float4 r; r.x = acc0; r.y = acc1; r.z = acc2; r.w = acc3;
  *(float4*)&out_t[((size_t)(p0 + px)) * 64 + cog * 4] = r;
}

// ------------------------------------------ bf16 Gram + fused top-8 candidates
// grid: 512 = B(4) * colblocks(32) * msplit(4); block 256 (4 waves)
__global__ __launch_bounds__(256, 2) void k_gram(const __hip_bfloat16* __restrict__ Xhi_,
                                                 const float* __restrict__ invn,
                                                 int* __restrict__ pidx) {
  __shared__ __align__(16) ushort_t sA[2][128 * 32];
  __shared__ __align__(16) ushort_t sB[2][128 * 32];
  __shared__ float slab[32 * 128];
  __shared__ float sic[128];
  __shared__ float sir[128];
  const ushort_t* Xhi = (const ushort_t*)Xhi_;
  int wg = blockIdx.x;
  int b = wg >> 7;
  int r0 = wg & 127;
  int cb = r0 & 31, sp = r0 >> 5;
  int colbase = cb * 128;
  int t = threadIdx.x;
  int w = t >> 6, lane = t & 63;
  int wr = 64 * (w >> 1), wc = 64 * (w & 1);
  const ushort_t* Xb = Xhi + (size_t)b * 4096 * 576;
  if (t < 128) sic[t] = invn[b * 4096 + colbase + t];
  float tlv[8];
  int tli[8];
#pragma unroll
  for (int j = 0; j < 8; ++j) { tlv[j] = -1e30f; tli[j] = 0; }

  const ushort_t* gB = Xb + (size_t)colbase * 576;

  for (int mt = 0; mt < 8; ++mt) {
    int rowbase = sp * 1024 + mt * 128;
    __syncthreads();
    if (t < 128) sir[t] = invn[b * 4096 + rowbase + t];
    f32x16 acc[2][2];
#pragma unroll
    for (int im = 0; im < 2; ++im)
#pragma unroll
      for (int il = 0; il < 2; ++il)
#pragma unroll
        for (int q = 0; q < 16; ++q) acc[im][il][q] = 0.f;

    const ushort_t* gA = Xb + (size_t)rowbase * 576;
    // stage chunk 0: tile = 128 rows x 32 bf16 = 8KB = 512 x 16B loads
    {
#pragma unroll
      for (int j = 0; j < 2; ++j) {
        int f = j * 256 + t;
        int r = f >> 2, sg = f & 3;
        gload_lds16(gA + (size_t)r * 576 + sg * 8, &sA[0][f * 8]);
        gload_lds16(gB + (size_t)r * 576 + sg * 8, &sB[0][f * 8]);
      }
    }
#pragma unroll 2
    for (int kc = 0; kc < 18; ++kc) {
      __syncthreads();
      if (kc < 17) {
        int buf = (kc + 1) & 1;
        const ushort_t* ga = gA + (kc + 1) * 32;
        const ushort_t* gb = gB + (kc + 1) * 32;
#pragma unroll
        for (int j = 0; j < 2; ++j) {
          int f = j * 256 + t;
          int r = f >> 2, sg = f & 3;
          gload_lds16(ga + (size_t)r * 576 + sg * 8, &sA[buf][f * 8]);
          gload_lds16(gb + (size_t)r * 576 + sg * 8, &sB[buf][f * 8]);
        }
      }
      const ushort_t* tA = sA[kc & 1];
      const ushort_t* tB = sB[kc & 1];
      int rr = lane & 31, half = lane >> 5;
#pragma unroll
      for (int ks = 0; ks < 2; ++ks) {
        short8 af[2], bf[2];
        af[0] = *(const short8*)&tA[(wr + rr) * 32 + ks * 16 + half * 8];
        af[1] = *(const short8*)&tA[(wr + 32 + rr) * 32 + ks * 16 + half * 8];
        bf[0] = *(const short8*)&tB[(wc + rr) * 32 + ks * 16 + half * 8];
        bf[1] = *(const short8*)&tB[(wc + 32 + rr) * 32 + ks * 16 + half * 8];
#pragma unroll
        for (int im = 0; im < 2; ++im)
#pragma unroll
          for (int il = 0; il < 2; ++il)
            acc[im][il] = __builtin_amdgcn_mfma_f32_32x32x16_bf16(
                af[im], bf[il], acc[im][il], 0, 0, 0);
      }
    }
    // fused top-k update, 32-row slabs
#pragma unroll
    for (int s = 0; s < 4; ++s) {
      __syncthreads();
      if ((w >> 1) == (s >> 1)) {
        int im = s & 1;
#pragma unroll
        for (int il = 0; il < 2; ++il) {
          int col = wc + 32 * il + (lane & 31);
#pragma unroll
          for (int reg = 0; reg < 16; ++reg) {
            int row = (reg & 3) + 8 * (reg >> 2) + 4 * (lane >> 5);
            slab[row * 128 + col] = acc[im][il][reg];
          }
        }
      }
      __syncthreads();
      if (t < 128) {
        float icol = sic[t];
#pragma unroll 1
        for (int v = 0; v < 32; ++v) {
          float val = slab[v * 128 + t] * sir[s * 32 + v] * icol;
          if (val > tlv[7]) {
            tlv[7] = val;
            tli[7] = rowbase + s * 32 + v;
#pragma unroll
            for (int j = 7; j > 0; --j) {
              if (tlv[j] > tlv[j - 1]) {
                float tv = tlv[j]; tlv[j] = tlv[j - 1]; tlv[j - 1] = tv;
                int ti = tli[j]; tli[j] = tli[j - 1]; tli[j - 1] = ti;
              }
            }
          }
        }
      }
    }
  }
  if (t < 128) {
    size_t base = (((size_t)b * 4 + sp) * 4096 + colbase + t) * 8;
#pragma unroll
    for (int j = 0; j < 8; ++j) pidx[base + j] = tli[j];
  }
}

// ------------------- exact f64 refinement of all 32 candidates + exact top-5
__global__ __launch_bounds__(256) void k_refine(const float* __restrict__ xt,
                                                const double* __restrict__ norm2,
                                                const int* __restrict__ pidx,
                                                float* __restrict__ Sval,
                                                int* __restrict__ Sidx) {
  int w = threadIdx.x >> 6, lane = threadIdx.x & 63;
  int gl = blockIdx.x * 4 + w;
  int b = gl >> 12, l = gl & 4095;
  int y = l >> 6, xq = l & 63;
  const float* xb = xt + ((size_t)b * 4096) * 64;
  int ci = 0;
  if (lane < 32) {
    int sp = lane >> 3, j = lane & 7;
    ci = pidx[(((size_t)b * 4 + sp) * 4096 + l) * 8 + j] & 4095;
  }
  float xl[9];
#pragma unroll
  for (int tap = 0; tap < 9; ++tap) {
    int kh = tap / 3, kw = tap % 3;
    xl[tap] = xb[(refl(y + kh - 1) * 64 + refl(xq + kw - 1)) * 64 + lane];
  }
  double nl = sqrt(norm2[b * 4096 + l]);
  if (nl < 1e-12) nl = 1e-12;
  double rv = -1e30;
  int ridx = 0x7fffffff;
#pragma unroll 1
  for (int r = 0; r < 32; ++r) {
    int m = __shfl(ci, r, 64);
    int my = m >> 6, mx = m & 63;
    double d = 0.0;
#pragma unroll
    for (int tap = 0; tap < 9; ++tap) {
      int kh = tap / 3, kw = tap % 3;
      float gv = xb[(refl(my + kh - 1) * 64 + refl(mx + kw - 1)) * 64 + lane];
      d += (double)xl[tap] * (double)gv;
    }
#pragma unroll
    for (int off = 32; off; off >>= 1) d += __shfl_xor(d, off, 64);
    double nm = sqrt(norm2[b * 4096 + m]);
    if (nm < 1e-12) nm = 1e-12;
    double R = d / (nl * nm);
    if (lane == r) { rv = R; ridx = m; }
  }
  // exact top-5 (rank 0 is self); emit ranks 1..4; ties -> lower index first
#pragma unroll
  for (int r = 0; r < 5; ++r) {
    double v = rv;
    int i = ridx;
#pragma unroll
    for (int off = 32; off; off >>= 1) {
      double ov = __shfl_xor(v, off, 64);
      int oi = __shfl_xor(i, off, 64);
      if (ov > v || (ov == v && oi < i)) { v = ov; i = oi; }
    }
    if (r >= 1 && lane == 0) {
      Sval[((size_t)b * 5 + r) * 4096 + l] = (float)v;
      Sidx[((size_t)b * 5 + r) * 4096 + l] = i;
    }
    if (rv == v && ridx == i) rv = -1e30;
  }
}

// ------------------------- fused fold/scale + composed 1x1 convs -> y (NCHW)
__global__ __launch_bounds__(256) void k_out(const float* __restrict__ xt,
                                             const float* __restrict__ feat,
                                             const float* __restrict__ Sval,
                                             const int* __restrict__ Sidx,
                                             const float* __restrict__ Wcat,
                                             const float* __restrict__ beff,
                                             float* __restrict__ out) {
  __shared__ float X[32 * 385];
  int t = threadIdx.x;
  int p0 = blockIdx.x * 32;
  int b = p0 >> 12, pl = p0 & 4095;
  {
    int lane = t & 63, grp = t >> 6;
#pragma unroll 1
    for (int j = 0; j < 8; ++j) {
      int px = grp * 8 + j;
      int p = pl + px;
      int y = p >> 6, xq = p & 63;
      X[px * 385 + lane] = feat[((size_t)b * 4096 + p) * 64 + lane];
      X[px * 385 + 64 + lane] = xt[((size_t)b * 4096 + p) * 64 + lane];
#pragma unroll 1
      for (int i = 1; i <= 4; ++i) {
        float S = Sval[((size_t)b * 5 + i) * 4096 + p];
        float a = 0.f;
#pragma unroll
        for (int tap = 0; tap < 9; ++tap) {
          int kh = tap / 3, kw = tap % 3;
          int qy = y + 1 - kh, qx = xq + 1 - kw;
          if (qy >= 0 && qy < 64 && qx >= 0 && qx < 64) {
            int m = Sidx[((size_t)b * 5 + i) * 4096 + qy * 64 + qx] & 4095;
            int gy = refl((m >> 6) + kh - 1), gx = refl((m & 63) + kw - 1);
            a += xt[((size_t)b * 4096 + gy * 64 + gx) * 64 + lane];
          }
        }
        X[px * 385 + 128 + (i - 1) * 64 + lane] = a * S * (1.f / 9.f);
      }
    }
  }
  __syncthreads();
  int px = t & 31, cog = t >> 5;
  float acc[8];
#pragma unroll
  for (int j = 0; j < 8; ++j) acc[j] = beff[cog * 8 + j];
#pragma unroll 2
  for (int k = 0; k < 384; ++k) {
    float xv = X[px * 385 + k];
    float4 w0 = *(const float4*)&Wcat[k * 64 + cog * 8];
    float4 w1 = *(const float4*)&Wcat[k * 64 + cog * 8 + 4];
    acc[0] += w0.x * xv; acc[1] += w0.y * xv;
    acc[2] += w0.z * xv; acc[3] += w0.w * xv;
    acc[4] += w1.x * xv; acc[5] += w1.y * xv;
    acc[6] += w1.z * xv; acc[7] += w1.w * xv;
  }
#pragma unroll
  for (int j = 0; j < 8; ++j)
    out[((size_t)b * 64 + cog * 8 + j) * 4096 + pl + px] = acc[j];
}

// ---------------------------------------------------------------------- launch
extern "C" void kernel_launch(void* const* d_in, const int* in_sizes, int n_in,
                              void* d_out, int out_size, void* d_ws, size_t ws_size,
                              hipStream_t stream) {
  const float* x = (const float*)d_in[0];
  const float* w1 = (const float*)d_in[1];
  const float* b1 = (const float*)d_in[2];
  const float* w2 = (const float*)d_in[3];
  const float* b2 = (const float*)d_in[4];
  const float* wt1 = (const float*)d_in[5];
  const float* bt1 = (const float*)d_in[6];
  const float* wt2 = (const float*)d_in[7];
  const float* bt2 = (const float*)d_in[8];

  char* ws = (char*)d_ws;
  float* x_t = (float*)(ws + 0);                       //  4 MB NHWC x
  float* y1 = (float*)(ws + 4194304);                  //  4 MB relu(conv1)
  float* feat = (float*)(ws + 8388608);                //  4 MB conv2
  __hip_bfloat16* Xhi = (__hip_bfloat16*)(ws + 12582912);  // 18.9 MB unfold bf16
  double* norm2 = (double*)(ws + 31457280);            // 128 KB
  float* invn = (float*)(ws + 31588352);               // 64 KB
  int* pidx = (int*)(ws + 31653888);                   //  2 MB
  float* Sval = (float*)(ws + 33751040);               // 320 KB
  int* Sidx = (int*)(ws + 34078720);                   // 320 KB
  float* W1t = (float*)(ws + 34406400);                // 144 KB
  float* W2t = (float*)(ws + 34553856);                // 144 KB
  float* Wcat = (float*)(ws + 34701312);               //  96 KB
  float* beff = (float*)(ws + 34799616);               // 256 B
  float* out = (float*)d_out;

  k_weights<<<dim3(385), dim3(256), 0, stream>>>(w1, w2, wt1, bt1, wt2, bt2,
                                                 W1t, W2t, Wcat, beff);
  k_transpose<<<dim3(256), dim3(256), 0, stream>>>(x, x_t);
  k_unfold<<<dim3(4096), dim3(256), 0, stream>>>(x_t, Xhi, norm2, invn);
  k_conv3x3<<<dim3(1024), dim3(256), 0, stream>>>(x_t, W1t, b1, y1, 1);
  k_conv3x3<<<dim3(1024), dim3(256), 0, stream>>>(y1, W2t, b2, feat, 0);
  k_gram<<<dim3(512), dim3(256), 0, stream>>>(Xhi, invn, pidx);
  k_refine<<<dim3(4096), dim3(256), 0, stream>>>(x_t, norm2, pidx, Sval, Sidx);
  k_out<<<dim3(512), dim3(256), 0, stream>>>(x_t, feat, Sval, Sidx, Wcat, beff, out);
}

// Round 3
// 743.390 us; speedup vs baseline: 1.0596x; 1.0596x over previous
//
#include <hip/hip_runtime.h>
#include <hip/hip_bf16.h>
#include <stdint.h>

typedef unsigned short ushort_t;
typedef __attribute__((ext_vector_type(8))) short short8;
typedef __attribute__((ext_vector_type(16))) float f32x16;

#define DEV __device__ __forceinline__

DEV int refl(int j) { return j < 0 ? -j : (j > 63 ? 126 - j : j); }

DEV void gload_lds16(const void* g, void* l) {
  __builtin_amdgcn_global_load_lds(
      (const __attribute__((address_space(1))) unsigned int*)g,
      (__attribute__((address_space(3))) unsigned int*)l, 16, 0, 0);
}

// ---------------------------------------------------------------- weights prep
__global__ __launch_bounds__(256) void k_weights(
    const float* __restrict__ w1, const float* __restrict__ w2,
    const float* __restrict__ wt1, const float* __restrict__ bt1,
    const float* __restrict__ wt2, const float* __restrict__ bt2,
    float* __restrict__ W1t, float* __restrict__ W2t,
    float* __restrict__ Wcat, float* __restrict__ beff) {
  int id = blockIdx.x * 256 + threadIdx.x;
  if (id < 36864) {
    int co = id & 63, k = id >> 6;
    int tap = k >> 6, ci = k & 63;
    W1t[k * 64 + co] = w1[(co * 64 + ci) * 9 + tap];
  } else if (id < 73728) {
    int rel = id - 36864;
    int co = rel & 63, k = rel >> 6;
    int tap = k >> 6, ci = k & 63;
    W2t[k * 64 + co] = w2[(co * 64 + ci) * 9 + tap];
  } else if (id < 81920) {
    int rel = id - 73728;
    int co = rel & 63, k = rel >> 6;  // k in [0,128)
    Wcat[k * 64 + co] = wt2[co * 192 + k];
  } else if (id < 98304) {
    int rel = id - 81920;
    int co = rel & 63, j = rel >> 6;  // j in [0,256)
    float s = 0.f;
    for (int ct = 0; ct < 64; ++ct) s += wt2[co * 192 + 128 + ct] * wt1[ct * 256 + j];
    Wcat[(128 + j) * 64 + co] = s;
  } else if (id < 98368) {
    int co = id - 98304;
    float s = bt2[co];
    for (int ct = 0; ct < 64; ++ct) s += wt2[co * 192 + 128 + ct] * bt1[ct];
    beff[co] = s;
  }
}

// ---------------------------------------------------------------- NCHW -> NHWC
__global__ __launch_bounds__(256) void k_transpose(const float* __restrict__ x,
                                                   float* __restrict__ xt) {
  __shared__ float tile[64][65];
  int wg = blockIdx.x;
  int b = wg >> 6, pt = wg & 63;
  int t = threadIdx.x;
  int lane = t & 63, grp = t >> 6;
  const float* xb = x + ((size_t)b * 64) * 4096 + pt * 64;
#pragma unroll
  for (int j = 0; j < 16; ++j) {
    int c = j * 4 + grp;
    tile[c][lane] = xb[(size_t)c * 4096 + lane];
  }
  __syncthreads();
  float* xtb = xt + ((size_t)b * 4096 + (size_t)pt * 64) * 64;
#pragma unroll
  for (int j = 0; j < 16; ++j) {
    int p = j * 4 + grp;
    xtb[p * 64 + lane] = tile[lane][p];
  }
}

// ------------------------------------ unfold (reflect) -> tiled bf16 + norms
// Xhi2 layout: [b*512+rb][kc(18)][seg(4)][r8(8)][e(8)], rb = l>>3, r8 = l&7,
// d = kc*32 + seg*8 + e. One block (512 thr, 8 waves) = one 8-pixel row-block.
__global__ __launch_bounds__(512) void k_unfold(const float* __restrict__ xt,
                                                ushort_t* __restrict__ Xhi2,
                                                double* __restrict__ dinv,
                                                float* __restrict__ invn) {
  __shared__ ushort_t U[4608];
  int rbg = blockIdx.x;           // 0..2047
  int b = rbg >> 9, rb = rbg & 511;
  int t = threadIdx.x;
  int p = t >> 6, lane = t & 63;  // wave p handles pixel l = rb*8+p, lane = channel
  int l = rb * 8 + p;
  int y = l >> 6, xq = l & 63;
  const float* xb = xt + ((size_t)b * 4096) * 64;
  double s = 0.0;
  int kcbase = (lane >> 5);        // c>=32 -> odd kc
  int seg = (lane & 31) >> 3, e = lane & 7;
#pragma unroll
  for (int tap = 0; tap < 9; ++tap) {
    int kh = tap / 3, kw = tap % 3;
    int gy = refl(y + kh - 1), gx = refl(xq + kw - 1);
    float v = xb[(gy * 64 + gx) * 64 + lane];
    __hip_bfloat16 h = __float2bfloat16(v);
    U[(tap * 2 + kcbase) * 256 + seg * 64 + p * 8 + e] = *(ushort_t*)&h;
    s += (double)v * (double)v;
  }
#pragma unroll
  for (int off = 32; off; off >>= 1) s += __shfl_xor(s, off, 64);
  if (lane == 0) {
    double n = sqrt(s);
    if (n < 1e-12) n = 1e-12;
    dinv[b * 4096 + l] = 1.0 / n;
    invn[b * 4096 + l] = (float)(1.0 / n);
  }
  __syncthreads();
  ushort_t* g = Xhi2 + (size_t)rbg * 4608;
#pragma unroll 1
  for (int i = t; i < 576; i += 512) {
    *(uint4*)&g[i * 8] = *(const uint4*)&U[i * 8];
  }
}

// ---------------------------------------------------------------- 3x3 conv f32
__global__ __launch_bounds__(256) void k_conv3x3(const float* __restrict__ in_t,
                                                 const float* __restrict__ Wt,
                                                 const float* __restrict__ bias,
                                                 float* __restrict__ out_t,
                                                 int do_relu) {
  __shared__ float X[16][580];
  int t = threadIdx.x;
  int p0 = blockIdx.x * 16;
  int b = p0 >> 12;
  int pl = p0 & 4095;
  const float* inb = in_t + ((size_t)b * 4096) * 64;
  {
    int lane = t & 63, grp = t >> 6;
#pragma unroll
    for (int j = 0; j < 4; ++j) {
      int px = grp * 4 + j;
      int p = pl + px;
      int y = p >> 6, xq = p & 63;
#pragma unroll
      for (int tap = 0; tap < 9; ++tap) {
        int kh = tap / 3, kw = tap % 3;
        int yy = y + kh - 1, xx = xq + kw - 1;
        float v = (yy >= 0 && yy < 64 && xx >= 0 && xx < 64)
                      ? inb[(yy * 64 + xx) * 64 + lane] : 0.f;
        X[px][tap * 64 + lane] = v;
      }
    }
  }
  __syncthreads();
  int px = t & 15, cog = t >> 4;
  const float* Wp = Wt + cog * 4;
  float acc0 = bias[cog * 4 + 0], acc1 = bias[cog * 4 + 1];
  float acc2 = bias[cog * 4 + 2], acc3 = bias[cog * 4 + 3];
#pragma unroll 2
  for (int k = 0; k < 576; k += 4) {
    float4 xv = *(const float4*)&X[px][k];
    float4 w0 = *(const float4*)&Wp[(k + 0) * 64];
    float4 w1 = *(const float4*)&Wp[(k + 1) * 64];
    float4 w2 = *(const float4*)&Wp[(k + 2) * 64];
    float4 w3 = *(const float4*)&Wp[(k + 3) * 64];
    acc0 += w0.x * xv.x + w1.x * xv.y + w2.x * xv.z + w3.x * xv.w;
    acc1 += w0.y * xv.x + w1.y * xv.y + w2.y * xv.z + w3.y * xv.w;
    acc2 += w0.z * xv.x + w1.z * xv.y + w2.z * xv.z + w3.z * xv.w;
    acc3 += w0.w * xv.x + w1.w * xv.y + w2.w * xv.z + w3.w * xv.w;
  }
  if (do_relu) {
    acc0 = fmaxf(acc0, 0.f); acc1 = fmaxf(acc1, 0.f);
    acc2 = fmaxf(acc2, 0.f); acc3 = fmaxf(acc3, 0.f);
  }
  float4 r; r.x = acc0; r.y = acc1; r.z = acc2; r.w = acc3;
  *(float4*)&out_t[((size_t)(p0 + px)) * 64 + cog * 4] = r;
}

// ------------------------------------------ bf16 Gram + fused top-8 candidates
// grid: 512 = B(4) * colblocks(32) * msplit(4); block 256 (4 waves)
// LDS tile slot f = (r>>3)*32 + seg*8 + (r&7); 16B/slot -> bank = (f&7)*4 ..+3
// => ds_read_b128 fragment reads are conflict-free.
__global__ __launch_bounds__(256, 2) void k_gram(const ushort_t* __restrict__ Xhi2,
                                                 const float* __restrict__ invn,
                                                 int* __restrict__ pidx) {
  __shared__ __align__(16) ushort_t sA[2][128 * 32];
  __shared__ __align__(16) ushort_t sB[2][128 * 32];
  __shared__ float slab[32 * 128];
  __shared__ float sic[128];
  __shared__ float sir[128];
  int wg = blockIdx.x;
  int b = wg >> 7;
  int r0 = wg & 127;
  int cb = r0 & 31, sp = r0 >> 5;
  int colbase = cb * 128;
  int t = threadIdx.x;
  int w = t >> 6, lane = t & 63;
  int wr = 64 * (w >> 1), wc = 64 * (w & 1);
  if (t < 128) sic[t] = invn[b * 4096 + colbase + t];
  float tlv[8];
  int tli[8];
#pragma unroll
  for (int j = 0; j < 8; ++j) { tlv[j] = -1e30f; tli[j] = 0; }

  const ushort_t* XB = Xhi2 + ((size_t)b * 512 + (colbase >> 3)) * 4608;

  for (int mt = 0; mt < 8; ++mt) {
    int rowbase = sp * 1024 + mt * 128;
    __syncthreads();
    if (t < 128) sir[t] = invn[b * 4096 + rowbase + t];
    f32x16 acc[2][2];
#pragma unroll
    for (int im = 0; im < 2; ++im)
#pragma unroll
      for (int il = 0; il < 2; ++il)
#pragma unroll
        for (int q = 0; q < 16; ++q) acc[im][il][q] = 0.f;

    const ushort_t* XA = Xhi2 + ((size_t)b * 512 + (rowbase >> 3)) * 4608;
    // stage chunk 0: 512 slots x 16B
    {
#pragma unroll
      for (int j = 0; j < 2; ++j) {
        int f = j * 256 + t;
        gload_lds16(XA + (size_t)(f >> 5) * 4608 + (f & 31) * 8, &sA[0][f * 8]);
        gload_lds16(XB + (size_t)(f >> 5) * 4608 + (f & 31) * 8, &sB[0][f * 8]);
      }
    }
#pragma unroll 2
    for (int kc = 0; kc < 18; ++kc) {
      __syncthreads();
      if (kc < 17) {
        int buf = (kc + 1) & 1;
        int ko = (kc + 1) * 256;
#pragma unroll
        for (int j = 0; j < 2; ++j) {
          int f = j * 256 + t;
          gload_lds16(XA + (size_t)(f >> 5) * 4608 + ko + (f & 31) * 8, &sA[buf][f * 8]);
          gload_lds16(XB + (size_t)(f >> 5) * 4608 + ko + (f & 31) * 8, &sB[buf][f * 8]);
        }
      }
      const ushort_t* tA = sA[kc & 1];
      const ushort_t* tB = sB[kc & 1];
      int rr = lane & 31, half = lane >> 5;
#pragma unroll
      for (int ks = 0; ks < 2; ++ks) {
        int fbase = (rr >> 3) * 32 + (ks * 2 + half) * 8 + (rr & 7);
        short8 af[2], bf[2];
        af[0] = *(const short8*)&tA[(wr * 4 + fbase) * 8];
        af[1] = *(const short8*)&tA[(wr * 4 + 128 + fbase) * 8];
        bf[0] = *(const short8*)&tB[(wc * 4 + fbase) * 8];
        bf[1] = *(const short8*)&tB[(wc * 4 + 128 + fbase) * 8];
#pragma unroll
        for (int im = 0; im < 2; ++im)
#pragma unroll
          for (int il = 0; il < 2; ++il)
            acc[im][il] = __builtin_amdgcn_mfma_f32_32x32x16_bf16(
                af[im], bf[il], acc[im][il], 0, 0, 0);
      }
    }
    // fused top-k update, 32-row slabs
#pragma unroll
    for (int s = 0; s < 4; ++s) {
      __syncthreads();
      if ((w >> 1) == (s >> 1)) {
        int im = s & 1;
#pragma unroll
        for (int il = 0; il < 2; ++il) {
          int col = wc + 32 * il + (lane & 31);
#pragma unroll
          for (int reg = 0; reg < 16; ++reg) {
            int row = (reg & 3) + 8 * (reg >> 2) + 4 * (lane >> 5);
            slab[row * 128 + col] = acc[im][il][reg];
          }
        }
      }
      __syncthreads();
      if (t < 128) {
        float icol = sic[t];
#pragma unroll 1
        for (int v = 0; v < 32; ++v) {
          float val = slab[v * 128 + t] * sir[s * 32 + v] * icol;
          if (val > tlv[7]) {
            tlv[7] = val;
            tli[7] = rowbase + s * 32 + v;
#pragma unroll
            for (int j = 7; j > 0; --j) {
              if (tlv[j] > tlv[j - 1]) {
                float tv = tlv[j]; tlv[j] = tlv[j - 1]; tlv[j - 1] = tv;
                int ti = tli[j]; tli[j] = tli[j - 1]; tli[j - 1] = ti;
              }
            }
          }
        }
      }
    }
  }
  if (t < 128) {
    size_t base = (((size_t)b * 4 + sp) * 4096 + colbase + t) * 8;
#pragma unroll
    for (int j = 0; j < 8; ++j) pidx[base + j] = tli[j];
  }
}

// ------------------- exact f64 refinement of all 32 candidates + exact top-5
__global__ __launch_bounds__(256) void k_refine(const float* __restrict__ xt,
                                                const double* __restrict__ dinv,
                                                const int* __restrict__ pidx,
                                                float* __restrict__ Sval,
                                                int* __restrict__ Sidx) {
  int w = threadIdx.x >> 6, lane = threadIdx.x & 63;
  int gl = blockIdx.x * 4 + w;
  int b = gl >> 12, l = gl & 4095;
  int y = l >> 6, xq = l & 63;
  const float* xb = xt + ((size_t)b * 4096) * 64;
  int ci = 0;
  if (lane < 32) {
    int sp = lane >> 3, j = lane & 7;
    ci = pidx[(((size_t)b * 4 + sp) * 4096 + l) * 8 + j] & 4095;
  }
  float xl[9];
#pragma unroll
  for (int tap = 0; tap < 9; ++tap) {
    int kh = tap / 3, kw = tap % 3;
    xl[tap] = xb[(refl(y + kh - 1) * 64 + refl(xq + kw - 1)) * 64 + lane];
  }
  double il = dinv[b * 4096 + l];
  double rv = -1e30;
  int ridx = 0x7fffffff;
#pragma unroll 1
  for (int r = 0; r < 32; ++r) {
    int m = __shfl(ci, r, 64);
    int my = m >> 6, mx = m & 63;
    double d = 0.0;
#pragma unroll
    for (int tap = 0; tap < 9; ++tap) {
      int kh = tap / 3, kw = tap % 3;
      float gv = xb[(refl(my + kh - 1) * 64 + refl(mx + kw - 1)) * 64 + lane];
      d += (double)xl[tap] * (double)gv;
    }
#pragma unroll
    for (int off = 32; off; off >>= 1) d += __shfl_xor(d, off, 64);
    double R = d * il * dinv[b * 4096 + m];
    if (lane == r) { rv = R; ridx = m; }
  }
  // exact top-5 (rank 0 is self); emit ranks 1..4; ties -> lower index first
#pragma unroll
  for (int r = 0; r < 5; ++r) {
    double v = rv;
    int i = ridx;
#pragma unroll
    for (int off = 32; off; off >>= 1) {
      double ov = __shfl_xor(v, off, 64);
      int oi = __shfl_xor(i, off, 64);
      if (ov > v || (ov == v && oi < i)) { v = ov; i = oi; }
    }
    if (r >= 1 && lane == 0) {
      Sval[((size_t)b * 5 + r) * 4096 + l] = (float)v;
      Sidx[((size_t)b * 5 + r) * 4096 + l] = i;
    }
    if (rv == v && ridx == i) rv = -1e30;
  }
}

// ------------------------- fused fold/scale + composed 1x1 convs -> y (NCHW)
__global__ __launch_bounds__(256) void k_out(const float* __restrict__ xt,
                                             const float* __restrict__ feat,
                                             const float* __restrict__ Sval,
                                             const int* __restrict__ Sidx,
                                             const float* __restrict__ Wcat,
                                             const float* __restrict__ beff,
                                             float* __restrict__ out) {
  __shared__ float X[32 * 385];
  int t = threadIdx.x;
  int p0 = blockIdx.x * 32;
  int b = p0 >> 12, pl = p0 & 4095;
  {
    int lane = t & 63, grp = t >> 6;
#pragma unroll 1
    for (int j = 0; j < 8; ++j) {
      int px = grp * 8 + j;
      int p = pl + px;
      int y = p >> 6, xq = p & 63;
      X[px * 385 + lane] = feat[((size_t)b * 4096 + p) * 64 + lane];
      X[px * 385 + 64 + lane] = xt[((size_t)b * 4096 + p) * 64 + lane];
#pragma unroll 1
      for (int i = 1; i <= 4; ++i) {
        float S = Sval[((size_t)b * 5 + i) * 4096 + p];
        float a = 0.f;
#pragma unroll
        for (int tap = 0; tap < 9; ++tap) {
          int kh = tap / 3, kw = tap % 3;
          int qy = y + 1 - kh, qx = xq + 1 - kw;
          if (qy >= 0 && qy < 64 && qx >= 0 && qx < 64) {
            int m = Sidx[((size_t)b * 5 + i) * 4096 + qy * 64 + qx] & 4095;
            int gy = refl((m >> 6) + kh - 1), gx = refl((m & 63) + kw - 1);
            a += xt[((size_t)b * 4096 + gy * 64 + gx) * 64 + lane];
          }
        }
        X[px * 385 + 128 + (i - 1) * 64 + lane] = a * S * (1.f / 9.f);
      }
    }
  }
  __syncthreads();
  int px = t & 31, cog = t >> 5;
  float acc[8];
#pragma unroll
  for (int j = 0; j < 8; ++j) acc[j] = beff[cog * 8 + j];
#pragma unroll 2
  for (int k = 0; k < 384; ++k) {
    float xv = X[px * 385 + k];
    float4 w0 = *(const float4*)&Wcat[k * 64 + cog * 8];
    float4 w1 = *(const float4*)&Wcat[k * 64 + cog * 8 + 4];
    acc[0] += w0.x * xv; acc[1] += w0.y * xv;
    acc[2] += w0.z * xv; acc[3] += w0.w * xv;
    acc[4] += w1.x * xv; acc[5] += w1.y * xv;
    acc[6] += w1.z * xv; acc[7] += w1.w * xv;
  }
#pragma unroll
  for (int j = 0; j < 8; ++j)
    out[((size_t)b * 64 + cog * 8 + j) * 4096 + pl + px] = acc[j];
}

// ---------------------------------------------------------------------- launch
extern "C" void kernel_launch(void* const* d_in, const int* in_sizes, int n_in,
                              void* d_out, int out_size, void* d_ws, size_t ws_size,
                              hipStream_t stream) {
  const float* x = (const float*)d_in[0];
  const float* w1 = (const float*)d_in[1];
  const float* b1 = (const float*)d_in[2];
  const float* w2 = (const float*)d_in[3];
  const float* b2 = (const float*)d_in[4];
  const float* wt1 = (const float*)d_in[5];
  const float* bt1 = (const float*)d_in[6];
  const float* wt2 = (const float*)d_in[7];
  const float* bt2 = (const float*)d_in[8];

  char* ws = (char*)d_ws;
  float* x_t = (float*)(ws + 0);                       //  4 MB NHWC x
  float* y1 = (float*)(ws + 4194304);                  //  4 MB relu(conv1)
  float* feat = (float*)(ws + 8388608);                //  4 MB conv2
  ushort_t* Xhi2 = (ushort_t*)(ws + 12582912);         // 18.9 MB tiled bf16 unfold
  double* dinv = (double*)(ws + 31457280);             // 128 KB f64 1/norm
  float* invn = (float*)(ws + 31588352);               // 64 KB
  int* pidx = (int*)(ws + 31653888);                   //  2 MB
  float* Sval = (float*)(ws + 33751040);               // 320 KB
  int* Sidx = (int*)(ws + 34078720);                   // 320 KB
  float* W1t = (float*)(ws + 34406400);                // 144 KB
  float* W2t = (float*)(ws + 34553856);                // 144 KB
  float* Wcat = (float*)(ws + 34701312);               //  96 KB
  float* beff = (float*)(ws + 34799616);               // 256 B
  float* out = (float*)d_out;

  k_weights<<<dim3(385), dim3(256), 0, stream>>>(w1, w2, wt1, bt1, wt2, bt2,
                                                 W1t, W2t, Wcat, beff);
  k_transpose<<<dim3(256), dim3(256), 0, stream>>>(x, x_t);
  k_unfold<<<dim3(2048), dim3(512), 0, stream>>>(x_t, Xhi2, dinv, invn);
  k_conv3x3<<<dim3(1024), dim3(256), 0, stream>>>(x_t, W1t, b1, y1, 1);
  k_conv3x3<<<dim3(1024), dim3(256), 0, stream>>>(y1, W2t, b2, feat, 0);
  k_gram<<<dim3(512), dim3(256), 0, stream>>>(Xhi2, invn, pidx);
  k_refine<<<dim3(4096), dim3(256), 0, stream>>>(x_t, dinv, pidx, Sval, Sidx);
  k_out<<<dim3(512), dim3(256), 0, stream>>>(x_t, feat, Sval, Sidx, Wcat, beff, out);
}

// Round 4
// 672.259 us; speedup vs baseline: 1.1717x; 1.1058x over previous
//
#include <hip/hip_runtime.h>
#include <hip/hip_bf16.h>
#include <stdint.h>

typedef unsigned short ushort_t;
typedef __attribute__((ext_vector_type(8))) short short8;
typedef __attribute__((ext_vector_type(16))) float f32x16;

#define DEV __device__ __forceinline__

DEV int refl(int j) { return j < 0 ? -j : (j > 63 ? 126 - j : j); }

DEV void gload_lds16(const void* g, void* l) {
  __builtin_amdgcn_global_load_lds(
      (const __attribute__((address_space(1))) unsigned int*)g,
      (__attribute__((address_space(3))) unsigned int*)l, 16, 0, 0);
}

// ---------------------------------------------------------------- weights prep
__global__ __launch_bounds__(256) void k_weights(
    const float* __restrict__ w1, const float* __restrict__ w2,
    const float* __restrict__ wt1, const float* __restrict__ bt1,
    const float* __restrict__ wt2, const float* __restrict__ bt2,
    float* __restrict__ W1t, float* __restrict__ W2t,
    float* __restrict__ Wcat, float* __restrict__ beff) {
  int id = blockIdx.x * 256 + threadIdx.x;
  if (id < 36864) {
    int co = id & 63, k = id >> 6;
    int tap = k >> 6, ci = k & 63;
    W1t[k * 64 + co] = w1[(co * 64 + ci) * 9 + tap];
  } else if (id < 73728) {
    int rel = id - 36864;
    int co = rel & 63, k = rel >> 6;
    int tap = k >> 6, ci = k & 63;
    W2t[k * 64 + co] = w2[(co * 64 + ci) * 9 + tap];
  } else if (id < 81920) {
    int rel = id - 73728;
    int co = rel & 63, k = rel >> 6;  // k in [0,128)
    Wcat[k * 64 + co] = wt2[co * 192 + k];
  } else if (id < 98304) {
    int rel = id - 81920;
    int co = rel & 63, j = rel >> 6;  // j in [0,256)
    float s = 0.f;
    for (int ct = 0; ct < 64; ++ct) s += wt2[co * 192 + 128 + ct] * wt1[ct * 256 + j];
    Wcat[(128 + j) * 64 + co] = s;
  } else if (id < 98368) {
    int co = id - 98304;
    float s = bt2[co];
    for (int ct = 0; ct < 64; ++ct) s += wt2[co * 192 + 128 + ct] * bt1[ct];
    beff[co] = s;
  }
}

// ---------------------------------------------------------------- NCHW -> NHWC
__global__ __launch_bounds__(256) void k_transpose(const float* __restrict__ x,
                                                   float* __restrict__ xt) {
  __shared__ float tile[64][65];
  int wg = blockIdx.x;
  int b = wg >> 6, pt = wg & 63;
  int t = threadIdx.x;
  int lane = t & 63, grp = t >> 6;
  const float* xb = x + ((size_t)b * 64) * 4096 + pt * 64;
#pragma unroll
  for (int j = 0; j < 16; ++j) {
    int c = j * 4 + grp;
    tile[c][lane] = xb[(size_t)c * 4096 + lane];
  }
  __syncthreads();
  float* xtb = xt + ((size_t)b * 4096 + (size_t)pt * 64) * 64;
#pragma unroll
  for (int j = 0; j < 16; ++j) {
    int p = j * 4 + grp;
    xtb[p * 64 + lane] = tile[lane][p];
  }
}

// ------------------------------------ unfold (reflect) -> tiled bf16 + norms
// Xhi2 layout: [b*512+rb][kc(18)][seg(4)][r8(8)][e(8)], rb = l>>3, r8 = l&7,
// d = kc*32 + seg*8 + e. One block (512 thr, 8 waves) = one 8-pixel row-block.
__global__ __launch_bounds__(512) void k_unfold(const float* __restrict__ xt,
                                                ushort_t* __restrict__ Xhi2,
                                                double* __restrict__ dinv,
                                                float* __restrict__ invn) {
  __shared__ ushort_t U[4608];
  int rbg = blockIdx.x;           // 0..2047
  int b = rbg >> 9, rb = rbg & 511;
  int t = threadIdx.x;
  int p = t >> 6, lane = t & 63;
  int l = rb * 8 + p;
  int y = l >> 6, xq = l & 63;
  const float* xb = xt + ((size_t)b * 4096) * 64;
  double s = 0.0;
  int kcbase = (lane >> 5);
  int seg = (lane & 31) >> 3, e = lane & 7;
#pragma unroll
  for (int tap = 0; tap < 9; ++tap) {
    int kh = tap / 3, kw = tap % 3;
    int gy = refl(y + kh - 1), gx = refl(xq + kw - 1);
    float v = xb[(gy * 64 + gx) * 64 + lane];
    __hip_bfloat16 h = __float2bfloat16(v);
    U[(tap * 2 + kcbase) * 256 + seg * 64 + p * 8 + e] = *(ushort_t*)&h;
    s += (double)v * (double)v;
  }
#pragma unroll
  for (int off = 32; off; off >>= 1) s += __shfl_xor(s, off, 64);
  if (lane == 0) {
    double n = sqrt(s);
    if (n < 1e-12) n = 1e-12;
    dinv[b * 4096 + l] = 1.0 / n;
    invn[b * 4096 + l] = (float)(1.0 / n);
  }
  __syncthreads();
  ushort_t* g = Xhi2 + (size_t)rbg * 4608;
#pragma unroll 1
  for (int i = t; i < 576; i += 512) {
    *(uint4*)&g[i * 8] = *(const uint4*)&U[i * 8];
  }
}

// ---------------------------------------------------------------- 3x3 conv f32
__global__ __launch_bounds__(256) void k_conv3x3(const float* __restrict__ in_t,
                                                 const float* __restrict__ Wt,
                                                 const float* __restrict__ bias,
                                                 float* __restrict__ out_t,
                                                 int do_relu) {
  __shared__ float X[16][580];
  int t = threadIdx.x;
  int p0 = blockIdx.x * 16;
  int b = p0 >> 12;
  int pl = p0 & 4095;
  const float* inb = in_t + ((size_t)b * 4096) * 64;
  {
    int lane = t & 63, grp = t >> 6;
#pragma unroll
    for (int j = 0; j < 4; ++j) {
      int px = grp * 4 + j;
      int p = pl + px;
      int y = p >> 6, xq = p & 63;
#pragma unroll
      for (int tap = 0; tap < 9; ++tap) {
        int kh = tap / 3, kw = tap % 3;
        int yy = y + kh - 1, xx = xq + kw - 1;
        float v = (yy >= 0 && yy < 64 && xx >= 0 && xx < 64)
                      ? inb[(yy * 64 + xx) * 64 + lane] : 0.f;
        X[px][tap * 64 + lane] = v;
      }
    }
  }
  __syncthreads();
  int px = t & 15, cog = t >> 4;
  const float* Wp = Wt + cog * 4;
  float acc0 = bias[cog * 4 + 0], acc1 = bias[cog * 4 + 1];
  float acc2 = bias[cog * 4 + 2], acc3 = bias[cog * 4 + 3];
#pragma unroll 2
  for (int k = 0; k < 576; k += 4) {
    float4 xv = *(const float4*)&X[px][k];
    float4 w0 = *(const float4*)&Wp[(k + 0) * 64];
    float4 w1 = *(const float4*)&Wp[(k + 1) * 64];
    float4 w2 = *(const float4*)&Wp[(k + 2) * 64];
    float4 w3 = *(const float4*)&Wp[(k + 3) * 64];
    acc0 += w0.x * xv.x + w1.x * xv.y + w2.x * xv.z + w3.x * xv.w;
    acc1 += w0.y * xv.x + w1.y * xv.y + w2.y * xv.z + w3.y * xv.w;
    acc2 += w0.z * xv.x + w1.z * xv.y + w2.z * xv.z + w3.z * xv.w;
    acc3 += w0.w * xv.x + w1.w * xv.y + w2.w * xv.z + w3.w * xv.w;
  }
  if (do_relu) {
    acc0 = fmaxf(acc0, 0.f); acc1 = fmaxf(acc1, 0.f);
    acc2 = fmaxf(acc2, 0.f); acc3 = fmaxf(acc3, 0.f);
  }
  float4 r; r.x = acc0; r.y = acc1; r.z = acc2; r.w = acc3;
  *(float4*)&out_t[((size_t)(p0 + px)) * 64 + cog * 4] = r;
}

// ------------------------------------------ bf16 Gram + in-register top-8
// grid: 1024 = 4/CU; block 256 (4 waves). Block: 64 cols (cb) x 1024 rows (sp),
// streamed as 8 mt-tiles of 128 rows. Wave w computes rows [32w,32w+32) of the
// tile vs all 64 cols; C-layout puts column 32*il+(lane&31) in lanes L,L^32,
// so lane L owns column L and keeps a register top-8 (no LDS slab, no slab
// barriers). End-of-kernel: 4 wave-lists merged via LDS (stride-33 pad).
// XCD swizzle: (wg&7)+8*(wg>>3&1) selects (b,sp) so each XCD's resident
// blocks share the streamed A-tiles (L2-resident).
__global__ __launch_bounds__(256, 4) void k_gram(const ushort_t* __restrict__ Xhi2,
                                                 const float* __restrict__ invn,
                                                 int* __restrict__ pidx) {
  __shared__ __align__(16) char lds[25600];
  ushort_t* sAb = (ushort_t*)lds;             // 2 bufs x 4096 ushorts (8KB each)
  ushort_t* sBb = (ushort_t*)(lds + 16384);   // 2 bufs x 2048 ushorts (4KB each)
  float* sir = (float*)(lds + 24576);         // 128 floats

  int wg = blockIdx.x;
  int u = wg & 7, v = wg >> 3;
  int bs = u + 8 * (v & 1);        // (b,sp) group: 2 per XCD
  int b = bs >> 2, sp = bs & 3;
  int cb = v >> 1;                 // 0..63
  int colbase = cb * 64;
  int t = threadIdx.x;
  int w = t >> 6, lane = t & 63;
  int rr = lane & 31, half = lane >> 5;

  const ushort_t* XB = Xhi2 + ((size_t)b * 512 + cb * 8) * 4608;

  float tlv[8];
  int tli[8];
#pragma unroll
  for (int j = 0; j < 8; ++j) { tlv[j] = -1e30f; tli[j] = 0; }

#pragma unroll 1
  for (int mt = 0; mt < 8; ++mt) {
    int rowbase = sp * 1024 + mt * 128;
    __syncthreads();   // prev mt list-update done (sir free), staging bufs free
    if (t < 128) sir[t] = invn[b * 4096 + rowbase + t];
    const ushort_t* XA = Xhi2 + ((size_t)b * 512 + sp * 128 + mt * 16) * 4608;
    f32x16 acc[2];
#pragma unroll
    for (int il = 0; il < 2; ++il)
#pragma unroll
      for (int q = 0; q < 16; ++q) acc[il][q] = 0.f;
    // prologue: stage kc=0 (A: 512 slots, B: 256 slots, 16B each)
    {
      int f1 = 256 + t;
      gload_lds16(XA + (size_t)(t >> 5) * 4608 + (t & 31) * 8, sAb + t * 8);
      gload_lds16(XA + (size_t)(f1 >> 5) * 4608 + (f1 & 31) * 8, sAb + f1 * 8);
      gload_lds16(XB + (size_t)(t >> 5) * 4608 + (t & 31) * 8, sBb + t * 8);
    }
#pragma unroll 1
    for (int kc = 0; kc < 18; ++kc) {
      __syncthreads();
      if (kc < 17) {
        int buf = (kc + 1) & 1;
        int ko = (kc + 1) * 256;
        int f1 = 256 + t;
        gload_lds16(XA + (size_t)(t >> 5) * 4608 + ko + (t & 31) * 8,
                    sAb + buf * 4096 + t * 8);
        gload_lds16(XA + (size_t)(f1 >> 5) * 4608 + ko + (f1 & 31) * 8,
                    sAb + buf * 4096 + f1 * 8);
        gload_lds16(XB + (size_t)(t >> 5) * 4608 + ko + (t & 31) * 8,
                    sBb + buf * 2048 + t * 8);
      }
      const ushort_t* tA = sAb + (kc & 1) * 4096;
      const ushort_t* tB = sBb + (kc & 1) * 2048;
#pragma unroll
      for (int ks = 0; ks < 2; ++ks) {
        int fb = (rr >> 3) * 32 + (ks * 2 + half) * 8 + (rr & 7);
        short8 af = *(const short8*)&tA[(w * 128 + fb) * 8];
        short8 bf0 = *(const short8*)&tB[fb * 8];
        short8 bf1 = *(const short8*)&tB[(128 + fb) * 8];
        acc[0] = __builtin_amdgcn_mfma_f32_32x32x16_bf16(af, bf0, acc[0], 0, 0, 0);
        acc[1] = __builtin_amdgcn_mfma_f32_32x32x16_bf16(af, bf1, acc[1], 0, 0, 0);
      }
    }
    // in-register top-8 update (sir written this mt, ordered by kc barriers)
    float4 sv[4];
    int rb0 = w * 32 + 4 * half;
    sv[0] = *(const float4*)&sir[rb0];
    sv[1] = *(const float4*)&sir[rb0 + 8];
    sv[2] = *(const float4*)&sir[rb0 + 16];
    sv[3] = *(const float4*)&sir[rb0 + 24];
    const float* svf = (const float*)sv;
#pragma unroll
    for (int il = 0; il < 2; ++il) {
#pragma unroll
      for (int reg = 0; reg < 16; ++reg) {
        float vv = acc[il][reg] * svf[reg];
        float vo = __shfl_xor(vv, 32, 64);
        if (half == il) {
          int rbase = rowbase + w * 32 + (reg & 3) + 8 * (reg >> 2);
          float v0 = vv;
          int i0 = rbase + 4 * half;
          if (v0 > tlv[7]) {
            tlv[7] = v0; tli[7] = i0;
#pragma unroll
            for (int j = 7; j > 0; --j)
              if (tlv[j] > tlv[j - 1]) {
                float tv = tlv[j]; tlv[j] = tlv[j - 1]; tlv[j - 1] = tv;
                int ti = tli[j]; tli[j] = tli[j - 1]; tli[j - 1] = ti;
              }
          }
          float v1 = vo;
          int i1 = rbase + 4 * (1 - half);
          if (v1 > tlv[7]) {
            tlv[7] = v1; tli[7] = i1;
#pragma unroll
            for (int j = 7; j > 0; --j)
              if (tlv[j] > tlv[j - 1]) {
                float tv = tlv[j]; tlv[j] = tlv[j - 1]; tlv[j - 1] = tv;
                int ti = tli[j]; tli[j] = tli[j - 1]; tli[j - 1] = ti;
              }
          }
        }
      }
    }
  }
  // merge 4 wave-lists -> top-8 per column
  __syncthreads();
  float* Mv = (float*)lds;
  int* Mi = (int*)(lds + 8448);
#pragma unroll
  for (int j = 0; j < 8; ++j) {
    Mv[lane * 33 + w * 8 + j] = tlv[j];
    Mi[lane * 33 + w * 8 + j] = tli[j];
  }
  __syncthreads();
  if (t < 64) {
    float bv[8];
    int bi[8];
#pragma unroll
    for (int j = 0; j < 8; ++j) { bv[j] = -1e30f; bi[j] = 0; }
#pragma unroll 1
    for (int i = 0; i < 32; ++i) {
      float vv = Mv[t * 33 + i];
      int ii = Mi[t * 33 + i];
      if (vv > bv[7]) {
        bv[7] = vv; bi[7] = ii;
#pragma unroll
        for (int j = 7; j > 0; --j)
          if (bv[j] > bv[j - 1]) {
            float tv = bv[j]; bv[j] = bv[j - 1]; bv[j - 1] = tv;
            int ti = bi[j]; bi[j] = bi[j - 1]; bi[j - 1] = ti;
          }
      }
    }
    size_t base = (((size_t)b * 4 + sp) * 4096 + colbase + t) * 8;
#pragma unroll
    for (int j = 0; j < 8; ++j) pidx[base + j] = bi[j];
  }
}

// ------------------- exact f64 refinement of all 32 candidates + exact top-5
__global__ __launch_bounds__(256) void k_refine(const float* __restrict__ xt,
                                                const double* __restrict__ dinv,
                                                const int* __restrict__ pidx,
                                                float* __restrict__ Sval,
                                                int* __restrict__ Sidx) {
  int w = threadIdx.x >> 6, lane = threadIdx.x & 63;
  int gl = blockIdx.x * 4 + w;
  int b = gl >> 12, l = gl & 4095;
  int y = l >> 6, xq = l & 63;
  const float* xb = xt + ((size_t)b * 4096) * 64;
  int ci = 0;
  if (lane < 32) {
    int sp = lane >> 3, j = lane & 7;
    ci = pidx[(((size_t)b * 4 + sp) * 4096 + l) * 8 + j] & 4095;
  }
  float xl[9];
#pragma unroll
  for (int tap = 0; tap < 9; ++tap) {
    int kh = tap / 3, kw = tap % 3;
    xl[tap] = xb[(refl(y + kh - 1) * 64 + refl(xq + kw - 1)) * 64 + lane];
  }
  double il = dinv[b * 4096 + l];
  double rv = -1e30;
  int ridx = 0x7fffffff;
#pragma unroll 1
  for (int r = 0; r < 32; ++r) {
    int m = __shfl(ci, r, 64);
    int my = m >> 6, mx = m & 63;
    double d = 0.0;
#pragma unroll
    for (int tap = 0; tap < 9; ++tap) {
      int kh = tap / 3, kw = tap % 3;
      float gv = xb[(refl(my + kh - 1) * 64 + refl(mx + kw - 1)) * 64 + lane];
      d += (double)xl[tap] * (double)gv;
    }
#pragma unroll
    for (int off = 32; off; off >>= 1) d += __shfl_xor(d, off, 64);
    double R = d * il * dinv[b * 4096 + m];
    if (lane == r) { rv = R; ridx = m; }
  }
  // exact top-5 (rank 0 is self); emit ranks 1..4; ties -> lower index first
#pragma unroll
  for (int r = 0; r < 5; ++r) {
    double v = rv;
    int i = ridx;
#pragma unroll
    for (int off = 32; off; off >>= 1) {
      double ov = __shfl_xor(v, off, 64);
      int oi = __shfl_xor(i, off, 64);
      if (ov > v || (ov == v && oi < i)) { v = ov; i = oi; }
    }
    if (r >= 1 && lane == 0) {
      Sval[((size_t)b * 5 + r) * 4096 + l] = (float)v;
      Sidx[((size_t)b * 5 + r) * 4096 + l] = i;
    }
    if (rv == v && ridx == i) rv = -1e30;
  }
}

// ------------------------- fused fold/scale + composed 1x1 convs -> y (NCHW)
__global__ __launch_bounds__(256) void k_out(const float* __restrict__ xt,
                                             const float* __restrict__ feat,
                                             const float* __restrict__ Sval,
                                             const int* __restrict__ Sidx,
                                             const float* __restrict__ Wcat,
                                             const float* __restrict__ beff,
                                             float* __restrict__ out) {
  __shared__ float X[32 * 385];
  int t = threadIdx.x;
  int p0 = blockIdx.x * 32;
  int b = p0 >> 12, pl = p0 & 4095;
  {
    int lane = t & 63, grp = t >> 6;
#pragma unroll 1
    for (int j = 0; j < 8; ++j) {
      int px = grp * 8 + j;
      int p = pl + px;
      int y = p >> 6, xq = p & 63;
      X[px * 385 + lane] = feat[((size_t)b * 4096 + p) * 64 + lane];
      X[px * 385 + 64 + lane] = xt[((size_t)b * 4096 + p) * 64 + lane];
#pragma unroll 1
      for (int i = 1; i <= 4; ++i) {
        float S = Sval[((size_t)b * 5 + i) * 4096 + p];
        float a = 0.f;
#pragma unroll
        for (int tap = 0; tap < 9; ++tap) {
          int kh = tap / 3, kw = tap % 3;
          int qy = y + 1 - kh, qx = xq + 1 - kw;
          if (qy >= 0 && qy < 64 && qx >= 0 && qx < 64) {
            int m = Sidx[((size_t)b * 5 + i) * 4096 + qy * 64 + qx] & 4095;
            int gy = refl((m >> 6) + kh - 1), gx = refl((m & 63) + kw - 1);
            a += xt[((size_t)b * 4096 + gy * 64 + gx) * 64 + lane];
          }
        }
        X[px * 385 + 128 + (i - 1) * 64 + lane] = a * S * (1.f / 9.f);
      }
    }
  }
  __syncthreads();
  int px = t & 31, cog = t >> 5;
  float acc[8];
#pragma unroll
  for (int j = 0; j < 8; ++j) acc[j] = beff[cog * 8 + j];
#pragma unroll 2
  for (int k = 0; k < 384; ++k) {
    float xv = X[px * 385 + k];
    float4 w0 = *(const float4*)&Wcat[k * 64 + cog * 8];
    float4 w1 = *(const float4*)&Wcat[k * 64 + cog * 8 + 4];
    acc[0] += w0.x * xv; acc[1] += w0.y * xv;
    acc[2] += w0.z * xv; acc[3] += w0.w * xv;
    acc[4] += w1.x * xv; acc[5] += w1.y * xv;
    acc[6] += w1.z * xv; acc[7] += w1.w * xv;
  }
#pragma unroll
  for (int j = 0; j < 8; ++j)
    out[((size_t)b * 64 + cog * 8 + j) * 4096 + pl + px] = acc[j];
}

// ---------------------------------------------------------------------- launch
extern "C" void kernel_launch(void* const* d_in, const int* in_sizes, int n_in,
                              void* d_out, int out_size, void* d_ws, size_t ws_size,
                              hipStream_t stream) {
  const float* x = (const float*)d_in[0];
  const float* w1 = (const float*)d_in[1];
  const float* b1 = (const float*)d_in[2];
  const float* w2 = (const float*)d_in[3];
  const float* b2 = (const float*)d_in[4];
  const float* wt1 = (const float*)d_in[5];
  const float* bt1 = (const float*)d_in[6];
  const float* wt2 = (const float*)d_in[7];
  const float* bt2 = (const float*)d_in[8];

  char* ws = (char*)d_ws;
  float* x_t = (float*)(ws + 0);                       //  4 MB NHWC x
  float* y1 = (float*)(ws + 4194304);                  //  4 MB relu(conv1)
  float* feat = (float*)(ws + 8388608);                //  4 MB conv2
  ushort_t* Xhi2 = (ushort_t*)(ws + 12582912);         // 18.9 MB tiled bf16 unfold
  double* dinv = (double*)(ws + 31457280);             // 128 KB f64 1/norm
  float* invn = (float*)(ws + 31588352);               // 64 KB
  int* pidx = (int*)(ws + 31653888);                   //  2 MB
  float* Sval = (float*)(ws + 33751040);               // 320 KB
  int* Sidx = (int*)(ws + 34078720);                   // 320 KB
  float* W1t = (float*)(ws + 34406400);                // 144 KB
  float* W2t = (float*)(ws + 34553856);                // 144 KB
  float* Wcat = (float*)(ws + 34701312);               //  96 KB
  float* beff = (float*)(ws + 34799616);               // 256 B
  float* out = (float*)d_out;

  k_weights<<<dim3(385), dim3(256), 0, stream>>>(w1, w2, wt1, bt1, wt2, bt2,
                                                 W1t, W2t, Wcat, beff);
  k_transpose<<<dim3(256), dim3(256), 0, stream>>>(x, x_t);
  k_unfold<<<dim3(2048), dim3(512), 0, stream>>>(x_t, Xhi2, dinv, invn);
  k_conv3x3<<<dim3(1024), dim3(256), 0, stream>>>(x_t, W1t, b1, y1, 1);
  k_conv3x3<<<dim3(1024), dim3(256), 0, stream>>>(y1, W2t, b2, feat, 0);
  k_gram<<<dim3(1024), dim3(256), 0, stream>>>(Xhi2, invn, pidx);
  k_refine<<<dim3(4096), dim3(256), 0, stream>>>(x_t, dinv, pidx, Sval, Sidx);
  k_out<<<dim3(512), dim3(256), 0, stream>>>(x_t, feat, Sval, Sidx, Wcat, beff, out);
}

// Round 5
// 620.163 us; speedup vs baseline: 1.2701x; 1.0840x over previous
//
#include <hip/hip_runtime.h>
#include <hip/hip_bf16.h>
#include <stdint.h>

typedef unsigned short ushort_t;
typedef __attribute__((ext_vector_type(8))) short short8;
typedef __attribute__((ext_vector_type(16))) float f32x16;

#define DEV __device__ __forceinline__

DEV int refl(int j) { return j < 0 ? -j : (j > 63 ? 126 - j : j); }

DEV void gload_lds16(const void* g, void* l) {
  __builtin_amdgcn_global_load_lds(
      (const __attribute__((address_space(1))) unsigned int*)g,
      (__attribute__((address_space(3))) unsigned int*)l, 16, 0, 0);
}

// packed candidate: monotone top-20 bits of float | 12-bit row index
DEV unsigned packval(float v, int idx) {
  unsigned u = __float_as_uint(v);
  u ^= (0x80000000u | (unsigned)((int)u >> 31));
  return (u & 0xFFFFF000u) | (unsigned)idx;
}

// sorted-desc 8-slot insert via max/min bubble-through (16 VALU, no branches)
DEV void ins8(unsigned (&s)[8], unsigned p) {
#pragma unroll
  for (int j = 0; j < 8; ++j) {
    unsigned mx = s[j] > p ? s[j] : p;
    unsigned mn = s[j] > p ? p : s[j];
    s[j] = mx;
    p = mn;
  }
}

// ---------------------------------------------------------------- weights prep
__global__ __launch_bounds__(256) void k_weights(
    const float* __restrict__ w1, const float* __restrict__ w2,
    const float* __restrict__ wt1, const float* __restrict__ bt1,
    const float* __restrict__ wt2, const float* __restrict__ bt2,
    float* __restrict__ W1t, float* __restrict__ W2t,
    float* __restrict__ Wcat, float* __restrict__ beff) {
  int id = blockIdx.x * 256 + threadIdx.x;
  if (id < 36864) {
    int co = id & 63, k = id >> 6;
    int tap = k >> 6, ci = k & 63;
    W1t[k * 64 + co] = w1[(co * 64 + ci) * 9 + tap];
  } else if (id < 73728) {
    int rel = id - 36864;
    int co = rel & 63, k = rel >> 6;
    int tap = k >> 6, ci = k & 63;
    W2t[k * 64 + co] = w2[(co * 64 + ci) * 9 + tap];
  } else if (id < 81920) {
    int rel = id - 73728;
    int co = rel & 63, k = rel >> 6;  // k in [0,128)
    Wcat[k * 64 + co] = wt2[co * 192 + k];
  } else if (id < 98304) {
    int rel = id - 81920;
    int co = rel & 63, j = rel >> 6;  // j in [0,256)
    float s = 0.f;
    for (int ct = 0; ct < 64; ++ct) s += wt2[co * 192 + 128 + ct] * wt1[ct * 256 + j];
    Wcat[(128 + j) * 64 + co] = s;
  } else if (id < 98368) {
    int co = id - 98304;
    float s = bt2[co];
    for (int ct = 0; ct < 64; ++ct) s += wt2[co * 192 + 128 + ct] * bt1[ct];
    beff[co] = s;
  }
}

// ---------------------------------------------------------------- NCHW -> NHWC
__global__ __launch_bounds__(256) void k_transpose(const float* __restrict__ x,
                                                   float* __restrict__ xt) {
  __shared__ float tile[64][65];
  int wg = blockIdx.x;
  int b = wg >> 6, pt = wg & 63;
  int t = threadIdx.x;
  int lane = t & 63, grp = t >> 6;
  const float* xb = x + ((size_t)b * 64) * 4096 + pt * 64;
#pragma unroll
  for (int j = 0; j < 16; ++j) {
    int c = j * 4 + grp;
    tile[c][lane] = xb[(size_t)c * 4096 + lane];
  }
  __syncthreads();
  float* xtb = xt + ((size_t)b * 4096 + (size_t)pt * 64) * 64;
#pragma unroll
  for (int j = 0; j < 16; ++j) {
    int p = j * 4 + grp;
    xtb[p * 64 + lane] = tile[lane][p];
  }
}

// ------------------------------------ unfold (reflect) -> tiled bf16 + norms
// Xhi2 layout: [b*512+rb][kc(18)][seg(4)][r8(8)][e(8)], rb = l>>3, r8 = l&7,
// d = kc*32 + seg*8 + e. One block (512 thr, 8 waves) = one 8-pixel row-block.
__global__ __launch_bounds__(512) void k_unfold(const float* __restrict__ xt,
                                                ushort_t* __restrict__ Xhi2,
                                                double* __restrict__ dinv,
                                                float* __restrict__ invn) {
  __shared__ ushort_t U[4608];
  int rbg = blockIdx.x;           // 0..2047
  int b = rbg >> 9, rb = rbg & 511;
  int t = threadIdx.x;
  int p = t >> 6, lane = t & 63;
  int l = rb * 8 + p;
  int y = l >> 6, xq = l & 63;
  const float* xb = xt + ((size_t)b * 4096) * 64;
  double s = 0.0;
  int kcbase = (lane >> 5);
  int seg = (lane & 31) >> 3, e = lane & 7;
#pragma unroll
  for (int tap = 0; tap < 9; ++tap) {
    int kh = tap / 3, kw = tap % 3;
    int gy = refl(y + kh - 1), gx = refl(xq + kw - 1);
    float v = xb[(gy * 64 + gx) * 64 + lane];
    __hip_bfloat16 h = __float2bfloat16(v);
    U[(tap * 2 + kcbase) * 256 + seg * 64 + p * 8 + e] = *(ushort_t*)&h;
    s += (double)v * (double)v;
  }
#pragma unroll
  for (int off = 32; off; off >>= 1) s += __shfl_xor(s, off, 64);
  if (lane == 0) {
    double n = sqrt(s);
    if (n < 1e-12) n = 1e-12;
    dinv[b * 4096 + l] = 1.0 / n;
    invn[b * 4096 + l] = (float)(1.0 / n);
  }
  __syncthreads();
  ushort_t* g = Xhi2 + (size_t)rbg * 4608;
#pragma unroll 1
  for (int i = t; i < 576; i += 512) {
    *(uint4*)&g[i * 8] = *(const uint4*)&U[i * 8];
  }
}

// ---------------------------------------------------------------- 3x3 conv f32
__global__ __launch_bounds__(256) void k_conv3x3(const float* __restrict__ in_t,
                                                 const float* __restrict__ Wt,
                                                 const float* __restrict__ bias,
                                                 float* __restrict__ out_t,
                                                 int do_relu) {
  __shared__ float X[16][580];
  int t = threadIdx.x;
  int p0 = blockIdx.x * 16;
  int b = p0 >> 12;
  int pl = p0 & 4095;
  const float* inb = in_t + ((size_t)b * 4096) * 64;
  {
    int lane = t & 63, grp = t >> 6;
#pragma unroll
    for (int j = 0; j < 4; ++j) {
      int px = grp * 4 + j;
      int p = pl + px;
      int y = p >> 6, xq = p & 63;
#pragma unroll
      for (int tap = 0; tap < 9; ++tap) {
        int kh = tap / 3, kw = tap % 3;
        int yy = y + kh - 1, xx = xq + kw - 1;
        float v = (yy >= 0 && yy < 64 && xx >= 0 && xx < 64)
                      ? inb[(yy * 64 + xx) * 64 + lane] : 0.f;
        X[px][tap * 64 + lane] = v;
      }
    }
  }
  __syncthreads();
  int px = t & 15, cog = t >> 4;
  const float* Wp = Wt + cog * 4;
  float acc0 = bias[cog * 4 + 0], acc1 = bias[cog * 4 + 1];
  float acc2 = bias[cog * 4 + 2], acc3 = bias[cog * 4 + 3];
#pragma unroll 2
  for (int k = 0; k < 576; k += 4) {
    float4 xv = *(const float4*)&X[px][k];
    float4 w0 = *(const float4*)&Wp[(k + 0) * 64];
    float4 w1 = *(const float4*)&Wp[(k + 1) * 64];
    float4 w2 = *(const float4*)&Wp[(k + 2) * 64];
    float4 w3 = *(const float4*)&Wp[(k + 3) * 64];
    acc0 += w0.x * xv.x + w1.x * xv.y + w2.x * xv.z + w3.x * xv.w;
    acc1 += w0.y * xv.x + w1.y * xv.y + w2.y * xv.z + w3.y * xv.w;
    acc2 += w0.z * xv.x + w1.z * xv.y + w2.z * xv.z + w3.z * xv.w;
    acc3 += w0.w * xv.x + w1.w * xv.y + w2.w * xv.z + w3.w * xv.w;
  }
  if (do_relu) {
    acc0 = fmaxf(acc0, 0.f); acc1 = fmaxf(acc1, 0.f);
    acc2 = fmaxf(acc2, 0.f); acc3 = fmaxf(acc3, 0.f);
  }
  float4 r; r.x = acc0; r.y = acc1; r.z = acc2; r.w = acc3;
  *(float4*)&out_t[((size_t)(p0 + px)) * 64 + cog * 4] = r;
}

// ------------------------------------------ bf16 Gram + in-register top-8
// grid: 1024 = 4/CU; block 256 (4 waves). Block: 64 cols x 1024 rows (sp),
// streamed as 8 mt-tiles of 128 rows. Lane L owns column colbase+L; candidates
// arrive packed (val20|idx12) and go through a branch-free max/min 8-slot
// insert. sic (column norm) dropped: positive per-column scale is order-
// invariant. End: 4 wave-lists merged via LDS.
__global__ __launch_bounds__(256, 4) void k_gram(const ushort_t* __restrict__ Xhi2,
                                                 const float* __restrict__ invn,
                                                 int* __restrict__ pidx) {
  __shared__ __align__(16) char lds[25600];
  ushort_t* sAb = (ushort_t*)lds;             // 2 bufs x 4096 ushorts (8KB each)
  ushort_t* sBb = (ushort_t*)(lds + 16384);   // 2 bufs x 2048 ushorts (4KB each)
  float* sir = (float*)(lds + 24576);         // 128 floats

  int wg = blockIdx.x;
  int u = wg & 7, v = wg >> 3;
  int bs = u + 8 * (v & 1);        // (b,sp) group: 2 per XCD
  int b = bs >> 2, sp = bs & 3;
  int cb = v >> 1;                 // 0..63
  int colbase = cb * 64;
  int t = threadIdx.x;
  int w = t >> 6, lane = t & 63;
  int rr = lane & 31, half = lane >> 5;

  const ushort_t* XB = Xhi2 + ((size_t)b * 512 + cb * 8) * 4608;

  unsigned list[8];
#pragma unroll
  for (int j = 0; j < 8; ++j) list[j] = 0u;

#pragma unroll 1
  for (int mt = 0; mt < 8; ++mt) {
    int rowbase = sp * 1024 + mt * 128;
    __syncthreads();   // prev mt topk done (sir free), staging bufs free
    if (t < 128) sir[t] = invn[b * 4096 + rowbase + t];
    const ushort_t* XA = Xhi2 + ((size_t)b * 512 + sp * 128 + mt * 16) * 4608;
    f32x16 acc[2];
#pragma unroll
    for (int il = 0; il < 2; ++il)
#pragma unroll
      for (int q = 0; q < 16; ++q) acc[il][q] = 0.f;
    // prologue: stage kc=0 (A: 512 slots, B: 256 slots, 16B each)
    {
      int f1 = 256 + t;
      gload_lds16(XA + (size_t)(t >> 5) * 4608 + (t & 31) * 8, sAb + t * 8);
      gload_lds16(XA + (size_t)(f1 >> 5) * 4608 + (f1 & 31) * 8, sAb + f1 * 8);
      gload_lds16(XB + (size_t)(t >> 5) * 4608 + (t & 31) * 8, sBb + t * 8);
    }
#pragma unroll 2
    for (int kc = 0; kc < 18; ++kc) {
      __syncthreads();
      if (kc < 17) {
        int buf = (kc + 1) & 1;
        int ko = (kc + 1) * 256;
        int f1 = 256 + t;
        gload_lds16(XA + (size_t)(t >> 5) * 4608 + ko + (t & 31) * 8,
                    sAb + buf * 4096 + t * 8);
        gload_lds16(XA + (size_t)(f1 >> 5) * 4608 + ko + (f1 & 31) * 8,
                    sAb + buf * 4096 + f1 * 8);
        gload_lds16(XB + (size_t)(t >> 5) * 4608 + ko + (t & 31) * 8,
                    sBb + buf * 2048 + t * 8);
      }
      const ushort_t* tA = sAb + (kc & 1) * 4096;
      const ushort_t* tB = sBb + (kc & 1) * 2048;
#pragma unroll
      for (int ks = 0; ks < 2; ++ks) {
        int fb = (rr >> 3) * 32 + (ks * 2 + half) * 8 + (rr & 7);
        short8 af = *(const short8*)&tA[(w * 128 + fb) * 8];
        short8 bf0 = *(const short8*)&tB[fb * 8];
        short8 bf1 = *(const short8*)&tB[(128 + fb) * 8];
        acc[0] = __builtin_amdgcn_mfma_f32_32x32x16_bf16(af, bf0, acc[0], 0, 0, 0);
        acc[1] = __builtin_amdgcn_mfma_f32_32x32x16_bf16(af, bf1, acc[1], 0, 0, 0);
      }
    }
    // branch-free packed top-8 update: 32 candidates/lane (own + partner rows)
    int rb_own = w * 32 + 4 * half;
    int rb_oth = w * 32 + 4 * (1 - half);
    float4 svo[4], svp[4];
#pragma unroll
    for (int q = 0; q < 4; ++q) {
      svo[q] = *(const float4*)&sir[rb_own + 8 * q];
      svp[q] = *(const float4*)&sir[rb_oth + 8 * q];
    }
    int base_own = rowbase + rb_own;
    int base_oth = rowbase + rb_oth;
#pragma unroll
    for (int reg = 0; reg < 16; ++reg) {
      int q = reg >> 2, jj = reg & 3;
      float a0 = acc[0][reg], a1 = acc[1][reg];
      float own = half ? a1 : a0;
      float oth = half ? a0 : a1;
      float rcv = __shfl_xor(oth, 32, 64);
      own *= ((const float*)&svo[q])[jj];
      rcv *= ((const float*)&svp[q])[jj];
      ins8(list, packval(own, base_own + 8 * q + jj));
      ins8(list, packval(rcv, base_oth + 8 * q + jj));
    }
  }
  // merge 4 wave-lists -> top-8 per column
  __syncthreads();
  unsigned* M = (unsigned*)lds;
#pragma unroll
  for (int j = 0; j < 8; ++j) M[lane * 33 + w * 8 + j] = list[j];
  __syncthreads();
  if (t < 64) {
    unsigned bl[8];
#pragma unroll
    for (int j = 0; j < 8; ++j) bl[j] = 0u;
#pragma unroll 1
    for (int i = 0; i < 32; ++i) ins8(bl, M[t * 33 + i]);
    size_t base = (((size_t)b * 4 + sp) * 4096 + colbase + t) * 8;
#pragma unroll
    for (int j = 0; j < 8; ++j) pidx[base + j] = (int)bl[j];
  }
}

// ------------------- exact f64 refinement of all 32 candidates + exact top-5
__global__ __launch_bounds__(256) void k_refine(const float* __restrict__ xt,
                                                const double* __restrict__ dinv,
                                                const int* __restrict__ pidx,
                                                float* __restrict__ Sval,
                                                int* __restrict__ Sidx) {
  int w = threadIdx.x >> 6, lane = threadIdx.x & 63;
  int gl = blockIdx.x * 4 + w;
  int b = gl >> 12, l = gl & 4095;
  int y = l >> 6, xq = l & 63;
  const float* xb = xt + ((size_t)b * 4096) * 64;
  int ci = 0;
  if (lane < 32) {
    int sp = lane >> 3, j = lane & 7;
    ci = pidx[(((size_t)b * 4 + sp) * 4096 + l) * 8 + j] & 4095;
  }
  float xl[9];
#pragma unroll
  for (int tap = 0; tap < 9; ++tap) {
    int kh = tap / 3, kw = tap % 3;
    xl[tap] = xb[(refl(y + kh - 1) * 64 + refl(xq + kw - 1)) * 64 + lane];
  }
  double il = dinv[b * 4096 + l];
  double rv = -1e30;
  int ridx = 0x7fffffff;
#pragma unroll 2
  for (int r = 0; r < 32; ++r) {
    int m = __shfl(ci, r, 64);
    int my = m >> 6, mx = m & 63;
    double d = 0.0;
#pragma unroll
    for (int tap = 0; tap < 9; ++tap) {
      int kh = tap / 3, kw = tap % 3;
      float gv = xb[(refl(my + kh - 1) * 64 + refl(mx + kw - 1)) * 64 + lane];
      d += (double)xl[tap] * (double)gv;
    }
#pragma unroll
    for (int off = 32; off; off >>= 1) d += __shfl_xor(d, off, 64);
    double R = d * il * dinv[b * 4096 + m];
    if (lane == r) { rv = R; ridx = m; }
  }
  // exact top-5 (rank 0 is self); emit ranks 1..4; ties -> lower index first
#pragma unroll
  for (int r = 0; r < 5; ++r) {
    double v = rv;
    int i = ridx;
#pragma unroll
    for (int off = 32; off; off >>= 1) {
      double ov = __shfl_xor(v, off, 64);
      int oi = __shfl_xor(i, off, 64);
      if (ov > v || (ov == v && oi < i)) { v = ov; i = oi; }
    }
    if (r >= 1 && lane == 0) {
      Sval[((size_t)b * 5 + r) * 4096 + l] = (float)v;
      Sidx[((size_t)b * 5 + r) * 4096 + l] = i;
    }
    if (rv == v && ridx == i) rv = -1e30;
  }
}

// ------------------------- fused fold/scale + composed 1x1 convs -> y (NCHW)
__global__ __launch_bounds__(256) void k_out(const float* __restrict__ xt,
                                             const float* __restrict__ feat,
                                             const float* __restrict__ Sval,
                                             const int* __restrict__ Sidx,
                                             const float* __restrict__ Wcat,
                                             const float* __restrict__ beff,
                                             float* __restrict__ out) {
  __shared__ float X[32 * 385];
  int t = threadIdx.x;
  int p0 = blockIdx.x * 32;
  int b = p0 >> 12, pl = p0 & 4095;
  {
    int lane = t & 63, grp = t >> 6;
#pragma unroll 1
    for (int j = 0; j < 8; ++j) {
      int px = grp * 8 + j;
      int p = pl + px;
      int y = p >> 6, xq = p & 63;
      X[px * 385 + lane] = feat[((size_t)b * 4096 + p) * 64 + lane];
      X[px * 385 + 64 + lane] = xt[((size_t)b * 4096 + p) * 64 + lane];
#pragma unroll 1
      for (int i = 1; i <= 4; ++i) {
        float S = Sval[((size_t)b * 5 + i) * 4096 + p];
        float a = 0.f;
#pragma unroll
        for (int tap = 0; tap < 9; ++tap) {
          int kh = tap / 3, kw = tap % 3;
          int qy = y + 1 - kh, qx = xq + 1 - kw;
          if (qy >= 0 && qy < 64 && qx >= 0 && qx < 64) {
            int m = Sidx[((size_t)b * 5 + i) * 4096 + qy * 64 + qx] & 4095;
            int gy = refl((m >> 6) + kh - 1), gx = refl((m & 63) + kw - 1);
            a += xt[((size_t)b * 4096 + gy * 64 + gx) * 64 + lane];
          }
        }
        X[px * 385 + 128 + (i - 1) * 64 + lane] = a * S * (1.f / 9.f);
      }
    }
  }
  __syncthreads();
  int px = t & 31, cog = t >> 5;
  float acc[8];
#pragma unroll
  for (int j = 0; j < 8; ++j) acc[j] = beff[cog * 8 + j];
#pragma unroll 2
  for (int k = 0; k < 384; ++k) {
    float xv = X[px * 385 + k];
    float4 w0 = *(const float4*)&Wcat[k * 64 + cog * 8];
    float4 w1 = *(const float4*)&Wcat[k * 64 + cog * 8 + 4];
    acc[0] += w0.x * xv; acc[1] += w0.y * xv;
    acc[2] += w0.z * xv; acc[3] += w0.w * xv;
    acc[4] += w1.x * xv; acc[5] += w1.y * xv;
    acc[6] += w1.z * xv; acc[7] += w1.w * xv;
  }
#pragma unroll
  for (int j = 0; j < 8; ++j)
    out[((size_t)b * 64 + cog * 8 + j) * 4096 + pl + px] = acc[j];
}

// ---------------------------------------------------------------------- launch
extern "C" void kernel_launch(void* const* d_in, const int* in_sizes, int n_in,
                              void* d_out, int out_size, void* d_ws, size_t ws_size,
                              hipStream_t stream) {
  const float* x = (const float*)d_in[0];
  const float* w1 = (const float*)d_in[1];
  const float* b1 = (const float*)d_in[2];
  const float* w2 = (const float*)d_in[3];
  const float* b2 = (const float*)d_in[4];
  const float* wt1 = (const float*)d_in[5];
  const float* bt1 = (const float*)d_in[6];
  const float* wt2 = (const float*)d_in[7];
  const float* bt2 = (const float*)d_in[8];

  char* ws = (char*)d_ws;
  float* x_t = (float*)(ws + 0);                       //  4 MB NHWC x
  float* y1 = (float*)(ws + 4194304);                  //  4 MB relu(conv1)
  float* feat = (float*)(ws + 8388608);                //  4 MB conv2
  ushort_t* Xhi2 = (ushort_t*)(ws + 12582912);         // 18.9 MB tiled bf16 unfold
  double* dinv = (double*)(ws + 31457280);             // 128 KB f64 1/norm
  float* invn = (float*)(ws + 31588352);               // 64 KB
  int* pidx = (int*)(ws + 31653888);                   //  2 MB
  float* Sval = (float*)(ws + 33751040);               // 320 KB
  int* Sidx = (int*)(ws + 34078720);                   // 320 KB
  float* W1t = (float*)(ws + 34406400);                // 144 KB
  float* W2t = (float*)(ws + 34553856);                // 144 KB
  float* Wcat = (float*)(ws + 34701312);               //  96 KB
  float* beff = (float*)(ws + 34799616);               // 256 B
  float* out = (float*)d_out;

  k_weights<<<dim3(385), dim3(256), 0, stream>>>(w1, w2, wt1, bt1, wt2, bt2,
                                                 W1t, W2t, Wcat, beff);
  k_transpose<<<dim3(256), dim3(256), 0, stream>>>(x, x_t);
  k_unfold<<<dim3(2048), dim3(512), 0, stream>>>(x_t, Xhi2, dinv, invn);
  k_conv3x3<<<dim3(1024), dim3(256), 0, stream>>>(x_t, W1t, b1, y1, 1);
  k_conv3x3<<<dim3(1024), dim3(256), 0, stream>>>(y1, W2t, b2, feat, 0);
  k_gram<<<dim3(1024), dim3(256), 0, stream>>>(Xhi2, invn, pidx);
  k_refine<<<dim3(4096), dim3(256), 0, stream>>>(x_t, dinv, pidx, Sval, Sidx);
  k_out<<<dim3(512), dim3(256), 0, stream>>>(x_t, feat, Sval, Sidx, Wcat, beff, out);
}

// Round 6
// 554.040 us; speedup vs baseline: 1.4217x; 1.1193x over previous
//
#include <hip/hip_runtime.h>
#include <hip/hip_bf16.h>
#include <stdint.h>

typedef unsigned short ushort_t;
typedef __attribute__((ext_vector_type(8))) short short8;
typedef __attribute__((ext_vector_type(16))) float f32x16;

#define DEV __device__ __forceinline__

DEV int refl(int j) { return j < 0 ? -j : (j > 63 ? 126 - j : j); }

DEV void gload_lds16(const void* g, void* l) {
  __builtin_amdgcn_global_load_lds(
      (const __attribute__((address_space(1))) unsigned int*)g,
      (__attribute__((address_space(3))) unsigned int*)l, 16, 0, 0);
}

// packed candidate: monotone top-20 bits of float | 12-bit row index
DEV unsigned packval(float v, int idx) {
  unsigned u = __float_as_uint(v);
  u ^= (0x80000000u | (unsigned)((int)u >> 31));
  return (u & 0xFFFFF000u) | (unsigned)idx;
}

// sorted-desc 8-slot insert via max/min bubble-through (16 VALU, no branches)
DEV void ins8(unsigned (&s)[8], unsigned p) {
#pragma unroll
  for (int j = 0; j < 8; ++j) {
    unsigned mx = s[j] > p ? s[j] : p;
    unsigned mn = s[j] > p ? p : s[j];
    s[j] = mx;
    p = mn;
  }
}

// ---------------------------------------------------------------- weights prep
__global__ __launch_bounds__(256) void k_weights(
    const float* __restrict__ w1, const float* __restrict__ w2,
    const float* __restrict__ wt1, const float* __restrict__ bt1,
    const float* __restrict__ wt2, const float* __restrict__ bt2,
    float* __restrict__ W1t, float* __restrict__ W2t,
    float* __restrict__ Wcat, float* __restrict__ beff) {
  int id = blockIdx.x * 256 + threadIdx.x;
  if (id < 36864) {
    int co = id & 63, k = id >> 6;
    int tap = k >> 6, ci = k & 63;
    W1t[k * 64 + co] = w1[(co * 64 + ci) * 9 + tap];
  } else if (id < 73728) {
    int rel = id - 36864;
    int co = rel & 63, k = rel >> 6;
    int tap = k >> 6, ci = k & 63;
    W2t[k * 64 + co] = w2[(co * 64 + ci) * 9 + tap];
  } else if (id < 81920) {
    int rel = id - 73728;
    int co = rel & 63, k = rel >> 6;  // k in [0,128)
    Wcat[k * 64 + co] = wt2[co * 192 + k];
  } else if (id < 98304) {
    int rel = id - 81920;
    int co = rel & 63, j = rel >> 6;  // j in [0,256)
    float s = 0.f;
    for (int ct = 0; ct < 64; ++ct) s += wt2[co * 192 + 128 + ct] * wt1[ct * 256 + j];
    Wcat[(128 + j) * 64 + co] = s;
  } else if (id < 98368) {
    int co = id - 98304;
    float s = bt2[co];
    for (int ct = 0; ct < 64; ++ct) s += wt2[co * 192 + 128 + ct] * bt1[ct];
    beff[co] = s;
  }
}

// ---------------------------------------------------------------- NCHW -> NHWC
__global__ __launch_bounds__(256) void k_transpose(const float* __restrict__ x,
                                                   float* __restrict__ xt) {
  __shared__ float tile[64][65];
  int wg = blockIdx.x;
  int b = wg >> 6, pt = wg & 63;
  int t = threadIdx.x;
  int lane = t & 63, grp = t >> 6;
  const float* xb = x + ((size_t)b * 64) * 4096 + pt * 64;
#pragma unroll
  for (int j = 0; j < 16; ++j) {
    int c = j * 4 + grp;
    tile[c][lane] = xb[(size_t)c * 4096 + lane];
  }
  __syncthreads();
  float* xtb = xt + ((size_t)b * 4096 + (size_t)pt * 64) * 64;
#pragma unroll
  for (int j = 0; j < 16; ++j) {
    int p = j * 4 + grp;
    xtb[p * 64 + lane] = tile[lane][p];
  }
}

// ------------------------------------ unfold (reflect) -> tiled bf16 + norms
// Xhi2 layout: [b*512+rb][kc(18)][seg(4)][r8(8)][e(8)], rb = l>>3, r8 = l&7,
// d = kc*32 + seg*8 + e. One block (512 thr, 8 waves) = one 8-pixel row-block.
__global__ __launch_bounds__(512) void k_unfold(const float* __restrict__ xt,
                                                ushort_t* __restrict__ Xhi2,
                                                double* __restrict__ dinv,
                                                float* __restrict__ invn) {
  __shared__ ushort_t U[4608];
  int rbg = blockIdx.x;           // 0..2047
  int b = rbg >> 9, rb = rbg & 511;
  int t = threadIdx.x;
  int p = t >> 6, lane = t & 63;
  int l = rb * 8 + p;
  int y = l >> 6, xq = l & 63;
  const float* xb = xt + ((size_t)b * 4096) * 64;
  double s = 0.0;
  int kcbase = (lane >> 5);
  int seg = (lane & 31) >> 3, e = lane & 7;
#pragma unroll
  for (int tap = 0; tap < 9; ++tap) {
    int kh = tap / 3, kw = tap % 3;
    int gy = refl(y + kh - 1), gx = refl(xq + kw - 1);
    float v = xb[(gy * 64 + gx) * 64 + lane];
    __hip_bfloat16 h = __float2bfloat16(v);
    U[(tap * 2 + kcbase) * 256 + seg * 64 + p * 8 + e] = *(ushort_t*)&h;
    s += (double)v * (double)v;
  }
#pragma unroll
  for (int off = 32; off; off >>= 1) s += __shfl_xor(s, off, 64);
  if (lane == 0) {
    double n = sqrt(s);
    if (n < 1e-12) n = 1e-12;
    dinv[b * 4096 + l] = 1.0 / n;
    invn[b * 4096 + l] = (float)(1.0 / n);
  }
  __syncthreads();
  ushort_t* g = Xhi2 + (size_t)rbg * 4608;
#pragma unroll 1
  for (int i = t; i < 576; i += 512) {
    *(uint4*)&g[i * 8] = *(const uint4*)&U[i * 8];
  }
}

// ---------------------------------------------------------------- 3x3 conv f32
__global__ __launch_bounds__(256) void k_conv3x3(const float* __restrict__ in_t,
                                                 const float* __restrict__ Wt,
                                                 const float* __restrict__ bias,
                                                 float* __restrict__ out_t,
                                                 int do_relu) {
  __shared__ float X[16][580];
  int t = threadIdx.x;
  int p0 = blockIdx.x * 16;
  int b = p0 >> 12;
  int pl = p0 & 4095;
  const float* inb = in_t + ((size_t)b * 4096) * 64;
  {
    int lane = t & 63, grp = t >> 6;
#pragma unroll
    for (int j = 0; j < 4; ++j) {
      int px = grp * 4 + j;
      int p = pl + px;
      int y = p >> 6, xq = p & 63;
#pragma unroll
      for (int tap = 0; tap < 9; ++tap) {
        int kh = tap / 3, kw = tap % 3;
        int yy = y + kh - 1, xx = xq + kw - 1;
        float v = (yy >= 0 && yy < 64 && xx >= 0 && xx < 64)
                      ? inb[(yy * 64 + xx) * 64 + lane] : 0.f;
        X[px][tap * 64 + lane] = v;
      }
    }
  }
  __syncthreads();
  int px = t & 15, cog = t >> 4;
  const float* Wp = Wt + cog * 4;
  float acc0 = bias[cog * 4 + 0], acc1 = bias[cog * 4 + 1];
  float acc2 = bias[cog * 4 + 2], acc3 = bias[cog * 4 + 3];
#pragma unroll 2
  for (int k = 0; k < 576; k += 4) {
    float4 xv = *(const float4*)&X[px][k];
    float4 w0 = *(const float4*)&Wp[(k + 0) * 64];
    float4 w1 = *(const float4*)&Wp[(k + 1) * 64];
    float4 w2 = *(const float4*)&Wp[(k + 2) * 64];
    float4 w3 = *(const float4*)&Wp[(k + 3) * 64];
    acc0 += w0.x * xv.x + w1.x * xv.y + w2.x * xv.z + w3.x * xv.w;
    acc1 += w0.y * xv.x + w1.y * xv.y + w2.y * xv.z + w3.y * xv.w;
    acc2 += w0.z * xv.x + w1.z * xv.y + w2.z * xv.z + w3.z * xv.w;
    acc3 += w0.w * xv.x + w1.w * xv.y + w2.w * xv.z + w3.w * xv.w;
  }
  if (do_relu) {
    acc0 = fmaxf(acc0, 0.f); acc1 = fmaxf(acc1, 0.f);
    acc2 = fmaxf(acc2, 0.f); acc3 = fmaxf(acc3, 0.f);
  }
  float4 r; r.x = acc0; r.y = acc1; r.z = acc2; r.w = acc3;
  *(float4*)&out_t[((size_t)(p0 + px)) * 64 + cog * 4] = r;
}

// ------------------------------------------ bf16 Gram + in-register top-8
__global__ __launch_bounds__(256, 4) void k_gram(const ushort_t* __restrict__ Xhi2,
                                                 const float* __restrict__ invn,
                                                 int* __restrict__ pidx) {
  __shared__ __align__(16) char lds[25600];
  ushort_t* sAb = (ushort_t*)lds;             // 2 bufs x 4096 ushorts (8KB each)
  ushort_t* sBb = (ushort_t*)(lds + 16384);   // 2 bufs x 2048 ushorts (4KB each)
  float* sir = (float*)(lds + 24576);         // 128 floats

  int wg = blockIdx.x;
  int u = wg & 7, v = wg >> 3;
  int bs = u + 8 * (v & 1);        // (b,sp) group: 2 per XCD
  int b = bs >> 2, sp = bs & 3;
  int cb = v >> 1;                 // 0..63
  int colbase = cb * 64;
  int t = threadIdx.x;
  int w = t >> 6, lane = t & 63;
  int rr = lane & 31, half = lane >> 5;

  const ushort_t* XB = Xhi2 + ((size_t)b * 512 + cb * 8) * 4608;

  unsigned list[8];
#pragma unroll
  for (int j = 0; j < 8; ++j) list[j] = 0u;

#pragma unroll 1
  for (int mt = 0; mt < 8; ++mt) {
    int rowbase = sp * 1024 + mt * 128;
    __syncthreads();   // prev mt topk done (sir free), staging bufs free
    if (t < 128) sir[t] = invn[b * 4096 + rowbase + t];
    const ushort_t* XA = Xhi2 + ((size_t)b * 512 + sp * 128 + mt * 16) * 4608;
    f32x16 acc[2];
#pragma unroll
    for (int il = 0; il < 2; ++il)
#pragma unroll
      for (int q = 0; q < 16; ++q) acc[il][q] = 0.f;
    // prologue: stage kc=0 (A: 512 slots, B: 256 slots, 16B each)
    {
      int f1 = 256 + t;
      gload_lds16(XA + (size_t)(t >> 5) * 4608 + (t & 31) * 8, sAb + t * 8);
      gload_lds16(XA + (size_t)(f1 >> 5) * 4608 + (f1 & 31) * 8, sAb + f1 * 8);
      gload_lds16(XB + (size_t)(t >> 5) * 4608 + (t & 31) * 8, sBb + t * 8);
    }
#pragma unroll 2
    for (int kc = 0; kc < 18; ++kc) {
      __syncthreads();
      if (kc < 17) {
        int buf = (kc + 1) & 1;
        int ko = (kc + 1) * 256;
        int f1 = 256 + t;
        gload_lds16(XA + (size_t)(t >> 5) * 4608 + ko + (t & 31) * 8,
                    sAb + buf * 4096 + t * 8);
        gload_lds16(XA + (size_t)(f1 >> 5) * 4608 + ko + (f1 & 31) * 8,
                    sAb + buf * 4096 + f1 * 8);
        gload_lds16(XB + (size_t)(t >> 5) * 4608 + ko + (t & 31) * 8,
                    sBb + buf * 2048 + t * 8);
      }
      const ushort_t* tA = sAb + (kc & 1) * 4096;
      const ushort_t* tB = sBb + (kc & 1) * 2048;
#pragma unroll
      for (int ks = 0; ks < 2; ++ks) {
        int fb = (rr >> 3) * 32 + (ks * 2 + half) * 8 + (rr & 7);
        short8 af = *(const short8*)&tA[(w * 128 + fb) * 8];
        short8 bf0 = *(const short8*)&tB[fb * 8];
        short8 bf1 = *(const short8*)&tB[(128 + fb) * 8];
        acc[0] = __builtin_amdgcn_mfma_f32_32x32x16_bf16(af, bf0, acc[0], 0, 0, 0);
        acc[1] = __builtin_amdgcn_mfma_f32_32x32x16_bf16(af, bf1, acc[1], 0, 0, 0);
      }
    }
    // branch-free packed top-8 update: 32 candidates/lane (own + partner rows)
    int rb_own = w * 32 + 4 * half;
    int rb_oth = w * 32 + 4 * (1 - half);
    float4 svo[4], svp[4];
#pragma unroll
    for (int q = 0; q < 4; ++q) {
      svo[q] = *(const float4*)&sir[rb_own + 8 * q];
      svp[q] = *(const float4*)&sir[rb_oth + 8 * q];
    }
    int base_own = rowbase + rb_own;
    int base_oth = rowbase + rb_oth;
#pragma unroll
    for (int reg = 0; reg < 16; ++reg) {
      int q = reg >> 2, jj = reg & 3;
      float a0 = acc[0][reg], a1 = acc[1][reg];
      float own = half ? a1 : a0;
      float oth = half ? a0 : a1;
      float rcv = __shfl_xor(oth, 32, 64);
      own *= ((const float*)&svo[q])[jj];
      rcv *= ((const float*)&svp[q])[jj];
      ins8(list, packval(own, base_own + 8 * q + jj));
      ins8(list, packval(rcv, base_oth + 8 * q + jj));
    }
  }
  // merge 4 wave-lists -> top-8 per column
  __syncthreads();
  unsigned* M = (unsigned*)lds;
#pragma unroll
  for (int j = 0; j < 8; ++j) M[lane * 33 + w * 8 + j] = list[j];
  __syncthreads();
  if (t < 64) {
    unsigned bl[8];
#pragma unroll
    for (int j = 0; j < 8; ++j) bl[j] = 0u;
#pragma unroll 1
    for (int i = 0; i < 32; ++i) ins8(bl, M[t * 33 + i]);
    size_t base = (((size_t)b * 4 + sp) * 4096 + colbase + t) * 8;
#pragma unroll
    for (int j = 0; j < 8; ++j) pidx[base + j] = (int)bl[j];
  }
}

// ------------------- exact f64 refinement of all 32 candidates + exact top-5
__global__ __launch_bounds__(256) void k_refine(const float* __restrict__ xt,
                                                const double* __restrict__ dinv,
                                                const int* __restrict__ pidx,
                                                float* __restrict__ Sval,
                                                int* __restrict__ Sidx) {
  int w = threadIdx.x >> 6, lane = threadIdx.x & 63;
  int gl = blockIdx.x * 4 + w;
  int b = gl >> 12, l = gl & 4095;
  int y = l >> 6, xq = l & 63;
  const float* xb = xt + ((size_t)b * 4096) * 64;
  int ci = 0;
  if (lane < 32) {
    int sp = lane >> 3, j = lane & 7;
    ci = pidx[(((size_t)b * 4 + sp) * 4096 + l) * 8 + j] & 4095;
  }
  float xl[9];
#pragma unroll
  for (int tap = 0; tap < 9; ++tap) {
    int kh = tap / 3, kw = tap % 3;
    xl[tap] = xb[(refl(y + kh - 1) * 64 + refl(xq + kw - 1)) * 64 + lane];
  }
  double il = dinv[b * 4096 + l];
  double rv = -1e30;
  int ridx = 0x7fffffff;
#pragma unroll 2
  for (int r = 0; r < 32; ++r) {
    int m = __shfl(ci, r, 64);
    int my = m >> 6, mx = m & 63;
    double d = 0.0;
#pragma unroll
    for (int tap = 0; tap < 9; ++tap) {
      int kh = tap / 3, kw = tap % 3;
      float gv = xb[(refl(my + kh - 1) * 64 + refl(mx + kw - 1)) * 64 + lane];
      d += (double)xl[tap] * (double)gv;
    }
#pragma unroll
    for (int off = 32; off; off >>= 1) d += __shfl_xor(d, off, 64);
    double R = d * il * dinv[b * 4096 + m];
    if (lane == r) { rv = R; ridx = m; }
  }
  // exact top-5 (rank 0 is self); emit ranks 1..4; ties -> lower index first
#pragma unroll
  for (int r = 0; r < 5; ++r) {
    double v = rv;
    int i = ridx;
#pragma unroll
    for (int off = 32; off; off >>= 1) {
      double ov = __shfl_xor(v, off, 64);
      int oi = __shfl_xor(i, off, 64);
      if (ov > v || (ov == v && oi < i)) { v = ov; i = oi; }
    }
    if (r >= 1 && lane == 0) {
      Sval[((size_t)b * 5 + r) * 4096 + l] = (float)v;
      Sidx[((size_t)b * 5 + r) * 4096 + l] = i;
    }
    if (rv == v && ridx == i) rv = -1e30;
  }
}

// ------------------------- fused fold/scale + composed 1x1 convs -> y (NCHW)
// 16 px/block, grid 1024 (4/CU). Stage A: prefetch Sidx halo (3x18x4) + Sval
// + feat/xt rows into LDS. Stage B: gathers with LDS-resident indices (high
// MLP, wave-uniform boundary branches). Stage C: 384-deep matvec, 4 out/thread.
__global__ __launch_bounds__(256, 4) void k_out(const float* __restrict__ xt,
                                                const float* __restrict__ feat,
                                                const float* __restrict__ Sval,
                                                const int* __restrict__ Sidx,
                                                const float* __restrict__ Wcat,
                                                const float* __restrict__ beff,
                                                float* __restrict__ out) {
  __shared__ float X[16 * 385];   // 24640 B
  __shared__ int SI[3 * 18 * 4];  // halo match indices, 0x7fffffff = outside
  __shared__ float SV[16 * 4];
  int t = threadIdx.x;
  int w = t >> 6, lane = t & 63;
  int p0 = blockIdx.x * 16;
  int b = p0 >> 12, pl = p0 & 4095;
  int y0 = pl >> 6, x0 = pl & 63;
  // ---- stage A: prefetch
  if (t < 216) {
    int r = t / 72, rem = t % 72;
    int c = rem >> 2, i = (rem & 3) + 1;
    int qy = y0 - 1 + r, qx = x0 - 1 + c;
    int m = 0x7fffffff;
    if (qy >= 0 && qy < 64 && qx >= 0 && qx < 64)
      m = Sidx[((size_t)b * 5 + i) * 4096 + qy * 64 + qx] & 4095;
    SI[(r * 18 + c) * 4 + (i - 1)] = m;
  }
  if (t < 64) {
    int px = t >> 2, i = (t & 3) + 1;
    SV[px * 4 + (i - 1)] = Sval[((size_t)b * 5 + i) * 4096 + pl + px];
  }
#pragma unroll
  for (int jj = 0; jj < 4; ++jj) {
    int px = w * 4 + jj;
    X[px * 385 + lane] = feat[((size_t)b * 4096 + pl + px) * 64 + lane];
    X[px * 385 + 64 + lane] = xt[((size_t)b * 4096 + pl + px) * 64 + lane];
  }
  __syncthreads();
  // ---- stage B: gathers. 64 (px,i) pairs; wave w owns pairs [16w,16w+16)
  const float* xb = xt + ((size_t)b * 4096) * 64;
#pragma unroll 4
  for (int k = 0; k < 16; ++k) {
    int pr = w * 16 + k;
    int px = pr >> 2, i = pr & 3;  // i rank-1 in 0..3
    float a = 0.f;
#pragma unroll
    for (int tap = 0; tap < 9; ++tap) {
      int kh = tap / 3, kw = tap % 3;
      int m = SI[((2 - kh) * 18 + px + 2 - kw) * 4 + i];
      if (m != 0x7fffffff) {
        int gy = refl((m >> 6) + kh - 1), gx = refl((m & 63) + kw - 1);
        a += xb[(gy * 64 + gx) * 64 + lane];
      }
    }
    X[px * 385 + 128 + i * 64 + lane] = a * SV[px * 4 + i] * (1.f / 9.f);
  }
  __syncthreads();
  // ---- stage C: matvec 384 -> 64, 4 outputs/thread
  int px = t & 15, cog = t >> 4;
  float4 acc = *(const float4*)&beff[cog * 4];
#pragma unroll 4
  for (int k = 0; k < 384; ++k) {
    float xv = X[px * 385 + k];
    float4 wv = *(const float4*)&Wcat[k * 64 + cog * 4];
    acc.x += wv.x * xv; acc.y += wv.y * xv;
    acc.z += wv.z * xv; acc.w += wv.w * xv;
  }
  size_t ob = ((size_t)b * 64 + cog * 4) * 4096 + pl + px;
  out[ob] = acc.x;
  out[ob + 4096] = acc.y;
  out[ob + 8192] = acc.z;
  out[ob + 12288] = acc.w;
}

// ---------------------------------------------------------------------- launch
extern "C" void kernel_launch(void* const* d_in, const int* in_sizes, int n_in,
                              void* d_out, int out_size, void* d_ws, size_t ws_size,
                              hipStream_t stream) {
  const float* x = (const float*)d_in[0];
  const float* w1 = (const float*)d_in[1];
  const float* b1 = (const float*)d_in[2];
  const float* w2 = (const float*)d_in[3];
  const float* b2 = (const float*)d_in[4];
  const float* wt1 = (const float*)d_in[5];
  const float* bt1 = (const float*)d_in[6];
  const float* wt2 = (const float*)d_in[7];
  const float* bt2 = (const float*)d_in[8];

  char* ws = (char*)d_ws;
  float* x_t = (float*)(ws + 0);                       //  4 MB NHWC x
  float* y1 = (float*)(ws + 4194304);                  //  4 MB relu(conv1)
  float* feat = (float*)(ws + 8388608);                //  4 MB conv2
  ushort_t* Xhi2 = (ushort_t*)(ws + 12582912);         // 18.9 MB tiled bf16 unfold
  double* dinv = (double*)(ws + 31457280);             // 128 KB f64 1/norm
  float* invn = (float*)(ws + 31588352);               // 64 KB
  int* pidx = (int*)(ws + 31653888);                   //  2 MB
  float* Sval = (float*)(ws + 33751040);               // 320 KB
  int* Sidx = (int*)(ws + 34078720);                   // 320 KB
  float* W1t = (float*)(ws + 34406400);                // 144 KB
  float* W2t = (float*)(ws + 34553856);                // 144 KB
  float* Wcat = (float*)(ws + 34701312);               //  96 KB
  float* beff = (float*)(ws + 34799616);               // 256 B
  float* out = (float*)d_out;

  k_weights<<<dim3(385), dim3(256), 0, stream>>>(w1, w2, wt1, bt1, wt2, bt2,
                                                 W1t, W2t, Wcat, beff);
  k_transpose<<<dim3(256), dim3(256), 0, stream>>>(x, x_t);
  k_unfold<<<dim3(2048), dim3(512), 0, stream>>>(x_t, Xhi2, dinv, invn);
  k_conv3x3<<<dim3(1024), dim3(256), 0, stream>>>(x_t, W1t, b1, y1, 1);
  k_conv3x3<<<dim3(1024), dim3(256), 0, stream>>>(y1, W2t, b2, feat, 0);
  k_gram<<<dim3(1024), dim3(256), 0, stream>>>(Xhi2, invn, pidx);
  k_refine<<<dim3(4096), dim3(256), 0, stream>>>(x_t, dinv, pidx, Sval, Sidx);
  k_out<<<dim3(1024), dim3(256), 0, stream>>>(x_t, feat, Sval, Sidx, Wcat, beff, out);
}